// Round 9
// baseline (458.047 us; speedup 1.0000x reference)
//
#include <hip/hip_runtime.h>

// ---------------------------------------------------------------------------
// MultiHeadSelfAttention: x[4,2048,768] -> (out[4,2048,768], att[4,12,2048,2048])
// Pipeline: cvt/transpose -> QKV GEMM (bf16 MFMA) -> fused attention -> proj GEMM
// R9 = R8 + vectorized LDS-bounce epilogue in k_gemm_qkv (kills scalar 2B stores)
// ---------------------------------------------------------------------------

typedef __attribute__((ext_vector_type(8)))  short          bf16x8;   // 8 bf16 (4 VGPR)
typedef __attribute__((ext_vector_type(4)))  float          f32x4;
typedef __attribute__((ext_vector_type(16))) float          f32x16;
typedef __attribute__((ext_vector_type(4)))  unsigned short us4;
typedef __attribute__((ext_vector_type(8)))  unsigned short us8;
typedef __attribute__((ext_vector_type(4)))  int            i32x4;
typedef __attribute__((ext_vector_type(4)))  unsigned int   u32x4;
typedef __attribute__((ext_vector_type(2)))  unsigned int   u32x2;

#define DEVFN static __device__ __forceinline__

enum : int { Bb = 4, Nn = 2048, Cc = 768, Hh = 12, Dd = 64, BH = 48, Mm = 8192, C3 = 2304 };

DEVFN unsigned short f2bf(float f) {
    unsigned int u = __float_as_uint(f);
    u = (u + 0x7fffu + ((u >> 16) & 1u)) >> 16;   // RNE
    return (unsigned short)u;
}

DEVFN void gload16(void* lds, const void* g) {
    __builtin_amdgcn_global_load_lds(
        (__attribute__((address_space(1))) void*)(g),
        (__attribute__((address_space(3))) void*)(lds), 16, 0, 0);
}

DEVFN f32x4 mfma_bf16(bf16x8 a, bf16x8 b, f32x4 c) {
    return __builtin_amdgcn_mfma_f32_16x16x32_bf16(a, b, c, 0, 0, 0);
}
DEVFN f32x16 mfma32(bf16x8 a, bf16x8 b, f32x16 c) {
    return __builtin_amdgcn_mfma_f32_32x32x16_bf16(a, b, c, 0, 0, 0);
}
DEVFN unsigned cvt_pk_bf16(float lo, float hi) {
    unsigned r;
    asm("v_cvt_pk_bf16_f32 %0, %1, %2" : "=v"(r) : "v"(lo), "v"(hi));
    return r;
}

// ---------------------------------------------------------------- cvt x->bf16
__global__ __launch_bounds__(256) void k_cvt_bf16(const float* __restrict__ in,
                                                  unsigned short* __restrict__ out, int n4) {
    int i = blockIdx.x * 256 + threadIdx.x;
    if (i < n4) {
        f32x4 v = ((const f32x4*)in)[i];
        us4 o;
        o[0] = f2bf(v[0]); o[1] = f2bf(v[1]); o[2] = f2bf(v[2]); o[3] = f2bf(v[3]);
        ((us4*)out)[i] = o;
    }
}

// ------------------------------------------------- transpose f32[R][C] -> bf16[C][R]
__global__ __launch_bounds__(256) void k_transpose_bf16(const float* __restrict__ in,
                                                        unsigned short* __restrict__ out,
                                                        int R, int Ccols) {
    __shared__ float t[64][65];
    int r0 = blockIdx.x * 64, c0 = blockIdx.y * 64;
    int tid = threadIdx.x;
#pragma unroll
    for (int i = 0; i < 16; i++) {
        int idx = i * 256 + tid; int lr = idx >> 6, lc = idx & 63;
        t[lr][lc] = in[(size_t)(r0 + lr) * Ccols + c0 + lc];
    }
    __syncthreads();
#pragma unroll
    for (int i = 0; i < 16; i++) {
        int idx = i * 256 + tid; int lc = idx >> 6, lr = idx & 63;
        out[(size_t)(c0 + lc) * R + r0 + lr] = f2bf(t[lr][lc]);
    }
}

// ------------------------------------------------------------- QKV GEMM
// Epilogue: acc -> bf16 LDS staging (V transposed at write) -> vectorized us8
// stores. Replaces 16 scalar 2B global stores/thread (partial-line RMW killer).
__global__ __launch_bounds__(256) void k_gemm_qkv(const unsigned short* __restrict__ A,
                                                  const unsigned short* __restrict__ Bt,
                                                  const float* __restrict__ bias,
                                                  unsigned short* __restrict__ qO,
                                                  unsigned short* __restrict__ kO,
                                                  unsigned short* __restrict__ vT) {
    __shared__ __align__(16) char smem[51200];
    char* AsB = smem;                 // [128][64] bf16 = 16384
    char* BsB = smem + 16384;         // [128][64] bf16 = 16384
    char* TsB = smem + 32768;         // epilogue staging, 18432 B
    int tid = threadIdx.x, lane = tid & 63, w = tid >> 6;
    int l15 = lane & 15, g = lane >> 4;
    int m0 = blockIdx.x * 128, n0 = blockIdx.y * 128;
    int wr = w >> 1, wc = w & 1;
    f32x4 acc[4][4] = {};

    for (int ks = 0; ks < 768; ks += 64) {
        __syncthreads();
#pragma unroll
        for (int i = 0; i < 4; i++) {
            int chunk = i * 256 + tid;
            int row = chunk >> 3, c8 = chunk & 7;
            gload16(AsB + chunk * 16, A + (size_t)(m0 + row) * 768 + ks + c8 * 8);
            gload16(BsB + chunk * 16, Bt + (size_t)(n0 + row) * 768 + ks + c8 * 8);
        }
        __syncthreads();
#pragma unroll
        for (int j = 0; j < 2; j++) {
            bf16x8 af[4], bf[4];
#pragma unroll
            for (int mb = 0; mb < 4; mb++) {
                int m = wr * 64 + mb * 16 + l15;
                af[mb] = *(const bf16x8*)(AsB + m * 128 + j * 64 + g * 16);
            }
#pragma unroll
            for (int nb = 0; nb < 4; nb++) {
                int n = wc * 64 + nb * 16 + l15;
                bf[nb] = *(const bf16x8*)(BsB + n * 128 + j * 64 + g * 16);
            }
#pragma unroll
            for (int mb = 0; mb < 4; mb++)
#pragma unroll
                for (int nb = 0; nb < 4; nb++)
                    acc[mb][nb] = mfma_bf16(af[mb], bf[nb], acc[mb][nb]);
        }
    }

    int which = n0 / 768;                 // 0=q 1=k 2=v (uniform per block)
    float bscale = (which == 0) ? 0.125f : 1.0f;
    unsigned short* Ts = (unsigned short*)TsB;

    for (int mh = 0; mh < 2; mh++) {      // two m-halves of 64 rows
        if (mh) __syncthreads();          // prior half's reads done
        if (wr == mh) {                   // waves owning this m-half stage
#pragma unroll
            for (int nb = 0; nb < 4; nb++) {
                int n_loc = wc * 64 + nb * 16 + l15;
                float bs = bias[n0 + n_loc];
#pragma unroll
                for (int mb = 0; mb < 4; mb++) {
                    f32x4 v = acc[mb][nb];
#pragma unroll
                    for (int r = 0; r < 4; r++) {
                        int m_loc = mb * 16 + g * 4 + r;
                        unsigned short bv = f2bf((v[r] + bs) * bscale);
                        if (which < 2)
                            Ts[m_loc * 136 + n_loc] = bv;      // [64][136]
                        else
                            Ts[n_loc * 72 + m_loc] = bv;       // [128][72] transposed
                    }
                }
            }
        }
        __syncthreads();
        if (which < 2) {
            // 64 rows x 2 heads; thread: row=tid>>2, head-half=(tid>>1)&1, quarter=tid&1
            int row = tid >> 2, hh = (tid >> 1) & 1, qq = tid & 1;
            int m_g = m0 + mh * 64 + row;
            int bI = m_g >> 11, tok = m_g & 2047;
            int h = ((n0 + hh * 64) - which * 768) >> 6;
            unsigned short* dst = (which == 0 ? qO : kO)
                                  + (size_t)((bI * 12 + h) * 2048 + tok) * 64 + qq * 32;
            const unsigned short* src = Ts + row * 136 + hh * 64 + qq * 32;
#pragma unroll
            for (int j = 0; j < 4; j++)
                *(us8*)(dst + j * 8) = *(const us8*)(src + j * 8);
        } else {
            // 128 d-rows; thread: drow=tid>>1, seg=tid&1 (32 toks = 64B)
            int drow = tid >> 1, seg = tid & 1;
            int n_g = n0 + drow;
            int h = (n_g - 1536) >> 6, d = n_g & 63;
            int bI = m0 >> 11;
            unsigned short* dst = vT + (size_t)((bI * 12 + h) * 64 + d) * 2048
                                  + (m0 & 2047) + mh * 64 + seg * 32;
            const unsigned short* src = Ts + drow * 72 + seg * 32;
#pragma unroll
            for (int j = 0; j < 4; j++)
                *(us8*)(dst + j * 8) = *(const us8*)(src + j * 8);
        }
    }
}

// ------------------------------------------------------------- fused attention
// (byte-identical to R8)
__global__ __launch_bounds__(256, 4) void k_attn(const unsigned short* __restrict__ qb,
                                                 const unsigned short* __restrict__ kbuf,
                                                 const unsigned short* __restrict__ vT,
                                                 const int* __restrict__ mask,
                                                 const float* __restrict__ pbias,
                                                 float* __restrict__ attO,
                                                 unsigned short* __restrict__ ctx) {
    __shared__ __align__(16) char smem[33408 + 512 + 128];
    float* Ssm    = (float*)smem;
    float* l_part = (float*)(smem + 33408);   // [4][32]
    float* rowinv = (float*)(smem + 33920);   // [32]

    int tid = threadIdx.x, lane = tid & 63, w = tid >> 6;   // w = 0..3
    int l31 = lane & 31, hi = lane >> 5;
    int n = blockIdx.x;
    int xcd = n & 7, slot = n >> 3;
    int bh = xcd * 6 + (slot >> 6), qt = slot & 63;
    int b = bh / 12, h = bh - b * 12;
    int q0 = qt * 32;
    (void)pbias;

    const unsigned short* kbase = kbuf + (size_t)bh * 2048 * 64;
    const unsigned short* vbase = vT + (size_t)bh * 64 * 2048;
    const int* mbase = mask + b * 2048 + hi * 4;

    bf16x8 qf0, qf1, qf2, qf3;
    {
        const unsigned short* qp = qb + (size_t)(bh * 2048 + q0 + l31) * 64 + hi * 8;
        qf0 = *(const bf16x8*)(qp);
        qf1 = *(const bf16x8*)(qp + 16);
        qf2 = *(const bf16x8*)(qp + 32);
        qf3 = *(const bf16x8*)(qp + 48);
    }
    const unsigned short* kp = kbase + (size_t)l31 * 64 + hi * 8;
    const unsigned short* vp = vbase + (size_t)l31 * 2048 + hi * 8;

    // ---------------- Phase A: lsum over wave's k-slice ----------------
    float lsum = 0.f;
#pragma unroll 2
    for (int t = 0; t < 16; t++) {
        int k0 = w * 512 + t * 32;
        const unsigned short* kpt = kp + (size_t)k0 * 64;
        bf16x8 kf0 = *(const bf16x8*)(kpt);
        bf16x8 kf1 = *(const bf16x8*)(kpt + 16);
        bf16x8 kf2 = *(const bf16x8*)(kpt + 32);
        bf16x8 kf3 = *(const bf16x8*)(kpt + 48);
        i32x4 m0 = *(const i32x4*)(mbase + k0);
        i32x4 m1 = *(const i32x4*)(mbase + k0 + 8);
        i32x4 m2 = *(const i32x4*)(mbase + k0 + 16);
        i32x4 m3 = *(const i32x4*)(mbase + k0 + 24);
        f32x16 s = {};
        s = mfma32(kf0, qf0, s);
        s = mfma32(kf1, qf1, s);
        s = mfma32(kf2, qf2, s);
        s = mfma32(kf3, qf3, s);
#pragma unroll
        for (int i = 0; i < 4; i++) lsum += m0[i] ? __expf(fminf(s[i], 75.f)) : 0.f;
#pragma unroll
        for (int i = 0; i < 4; i++) lsum += m1[i] ? __expf(fminf(s[4 + i], 75.f)) : 0.f;
#pragma unroll
        for (int i = 0; i < 4; i++) lsum += m2[i] ? __expf(fminf(s[8 + i], 75.f)) : 0.f;
#pragma unroll
        for (int i = 0; i < 4; i++) lsum += m3[i] ? __expf(fminf(s[12 + i], 75.f)) : 0.f;
    }
    lsum += __shfl_xor(lsum, 32, 64);
    if (hi == 0) l_part[w * 32 + l31] = lsum;
    __syncthreads();
    if (tid < 32)
        rowinv[tid] = 1.0f / (l_part[tid] + l_part[32 + tid] + l_part[64 + tid] + l_part[96 + tid]);
    __syncthreads();
    float rinv = rowinv[l31];

    // ---------------- Phase B: 8 phases of 256 k ----------------
    f32x16 c0 = {}, c1 = {};
    for (int p = 0; p < 8; p++) {
#pragma unroll
        for (int t = 0; t < 2; t++) {
            int kq0 = w * 64 + t * 32;
            int k0 = p * 256 + kq0;
            const unsigned short* kpt = kp + (size_t)k0 * 64;
            bf16x8 kf0 = *(const bf16x8*)(kpt);
            bf16x8 kf1 = *(const bf16x8*)(kpt + 16);
            bf16x8 kf2 = *(const bf16x8*)(kpt + 32);
            bf16x8 kf3 = *(const bf16x8*)(kpt + 48);
            bf16x8 vf00 = *(const bf16x8*)(vp + k0);
            bf16x8 vf01 = *(const bf16x8*)(vp + k0 + 16);
            bf16x8 vf10 = *(const bf16x8*)(vp + 65536 + k0);
            bf16x8 vf11 = *(const bf16x8*)(vp + 65536 + k0 + 16);
            i32x4 m0 = *(const i32x4*)(mbase + k0);
            i32x4 m1 = *(const i32x4*)(mbase + k0 + 8);
            i32x4 m2 = *(const i32x4*)(mbase + k0 + 16);
            i32x4 m3 = *(const i32x4*)(mbase + k0 + 24);
            f32x16 s = {};
            s = mfma32(kf0, qf0, s);
            s = mfma32(kf1, qf1, s);
            s = mfma32(kf2, qf2, s);
            s = mfma32(kf3, qf3, s);

            float* srow = Ssm + l31 * 261 + kq0 + 4 * hi;
            unsigned pk00, pk01, pk10, pk11, pk20, pk21, pk30, pk31;
            {
                float a0 = (m0[0] ? __expf(fminf(s[0], 75.f)) : 0.f) * rinv;
                float a1 = (m0[1] ? __expf(fminf(s[1], 75.f)) : 0.f) * rinv;
                float a2 = (m0[2] ? __expf(fminf(s[2], 75.f)) : 0.f) * rinv;
                float a3 = (m0[3] ? __expf(fminf(s[3], 75.f)) : 0.f) * rinv;
                f32x4 av = {a0, a1, a2, a3};
                *(f32x4*)(srow) = av;
                pk00 = cvt_pk_bf16(a0, a1); pk01 = cvt_pk_bf16(a2, a3);
            }
            {
                float a0 = (m1[0] ? __expf(fminf(s[4], 75.f)) : 0.f) * rinv;
                float a1 = (m1[1] ? __expf(fminf(s[5], 75.f)) : 0.f) * rinv;
                float a2 = (m1[2] ? __expf(fminf(s[6], 75.f)) : 0.f) * rinv;
                float a3 = (m1[3] ? __expf(fminf(s[7], 75.f)) : 0.f) * rinv;
                f32x4 av = {a0, a1, a2, a3};
                *(f32x4*)(srow + 8) = av;
                pk10 = cvt_pk_bf16(a0, a1); pk11 = cvt_pk_bf16(a2, a3);
            }
            {
                float a0 = (m2[0] ? __expf(fminf(s[8], 75.f)) : 0.f) * rinv;
                float a1 = (m2[1] ? __expf(fminf(s[9], 75.f)) : 0.f) * rinv;
                float a2 = (m2[2] ? __expf(fminf(s[10], 75.f)) : 0.f) * rinv;
                float a3 = (m2[3] ? __expf(fminf(s[11], 75.f)) : 0.f) * rinv;
                f32x4 av = {a0, a1, a2, a3};
                *(f32x4*)(srow + 16) = av;
                pk20 = cvt_pk_bf16(a0, a1); pk21 = cvt_pk_bf16(a2, a3);
            }
            {
                float a0 = (m3[0] ? __expf(fminf(s[12], 75.f)) : 0.f) * rinv;
                float a1 = (m3[1] ? __expf(fminf(s[13], 75.f)) : 0.f) * rinv;
                float a2 = (m3[2] ? __expf(fminf(s[14], 75.f)) : 0.f) * rinv;
                float a3 = (m3[3] ? __expf(fminf(s[15], 75.f)) : 0.f) * rinv;
                f32x4 av = {a0, a1, a2, a3};
                *(f32x4*)(srow + 24) = av;
                pk30 = cvt_pk_bf16(a0, a1); pk31 = cvt_pk_bf16(a2, a3);
            }
            {
                u32x2 sA = __builtin_amdgcn_permlane32_swap(pk00, pk10, false, false);
                u32x2 sB = __builtin_amdgcn_permlane32_swap(pk01, pk11, false, false);
                u32x4 bi = {sA[0], sB[0], sA[1], sB[1]};
                bf16x8 pf = __builtin_bit_cast(bf16x8, bi);
                c0 = mfma32(vf00, pf, c0);
                c1 = mfma32(vf10, pf, c1);
            }
            {
                u32x2 sA = __builtin_amdgcn_permlane32_swap(pk20, pk30, false, false);
                u32x2 sB = __builtin_amdgcn_permlane32_swap(pk21, pk31, false, false);
                u32x4 bi = {sA[0], sB[0], sA[1], sB[1]};
                bf16x8 pf = __builtin_bit_cast(bf16x8, bi);
                c0 = mfma32(vf01, pf, c0);
                c1 = mfma32(vf11, pf, c1);
            }
        }
        __syncthreads();
        {
            int c16 = lane & 15;
#pragma unroll
            for (int jj = 0; jj < 2; jj++) {
                int row = 8 * w + 4 * jj + (lane >> 4);
                const float* src = Ssm + row * 261 + c16 * 4;
                float* dst = attO + ((size_t)(bh * 2048 + q0 + row)) * 2048 + p * 256 + c16 * 4;
#pragma unroll
                for (int j = 0; j < 4; j++)
                    __builtin_nontemporal_store(*(const f32x4*)(src + j * 64),
                                                (f32x4*)(dst + j * 64));
            }
        }
        __syncthreads();
    }

    // ---------------- ctx: two-step wave-partial reduction ----------------
    {
        float* cw = Ssm + w * 2080 + l31 * 65;   // [4][32][65] overlay
#pragma unroll
        for (int r = 0; r < 16; r++) {
            int d = (r & 3) + 8 * (r >> 2) + 4 * hi;
            cw[d] = c0[r];
            cw[d + 32] = c1[r];
        }
    }
    __syncthreads();
    {
        int q = tid >> 3, d0 = (tid & 7) * 8;
        float a[8];
#pragma unroll
        for (int j = 0; j < 8; j++) a[j] = 0.f;
#pragma unroll
        for (int w2 = 0; w2 < 4; w2++) {
            const float* cw = Ssm + w2 * 2080 + q * 65 + d0;
#pragma unroll
            for (int j = 0; j < 8; j++) a[j] += cw[j];
        }
        us4 o0, o1;
        o0[0] = f2bf(a[0]); o0[1] = f2bf(a[1]); o0[2] = f2bf(a[2]); o0[3] = f2bf(a[3]);
        o1[0] = f2bf(a[4]); o1[1] = f2bf(a[5]); o1[2] = f2bf(a[6]); o1[3] = f2bf(a[7]);
        unsigned short* cp = ctx + (size_t)(b * 2048 + q0 + q) * 768 + h * 64 + d0;
        *(us4*)(cp) = o0;
        *(us4*)(cp + 4) = o1;
    }
}

// ------------------------------------------------------------- proj GEMM
__global__ __launch_bounds__(256) void k_gemm_proj(const unsigned short* __restrict__ A,
                                                   const unsigned short* __restrict__ Bt,
                                                   const float* __restrict__ bias,
                                                   float* __restrict__ out) {
    __shared__ __align__(16) unsigned short As[128 * 64];
    __shared__ __align__(16) unsigned short Bs[128 * 64];
    char* AsB = (char*)As; char* BsB = (char*)Bs;
    int tid = threadIdx.x, lane = tid & 63, w = tid >> 6;
    int l15 = lane & 15, g = lane >> 4;
    int m0 = blockIdx.x * 128, n0 = blockIdx.y * 128;
    int wr = w >> 1, wc = w & 1;
    f32x4 acc[4][4] = {};

    for (int ks = 0; ks < 768; ks += 64) {
        __syncthreads();
#pragma unroll
        for (int i = 0; i < 4; i++) {
            int chunk = i * 256 + tid;
            int row = chunk >> 3, c8 = chunk & 7;
            gload16(AsB + chunk * 16, A + (size_t)(m0 + row) * 768 + ks + c8 * 8);
            gload16(BsB + chunk * 16, Bt + (size_t)(n0 + row) * 768 + ks + c8 * 8);
        }
        __syncthreads();
#pragma unroll
        for (int j = 0; j < 2; j++) {
            bf16x8 af[4], bf[4];
#pragma unroll
            for (int mb = 0; mb < 4; mb++) {
                int m = wr * 64 + mb * 16 + l15;
                af[mb] = *(const bf16x8*)(AsB + m * 128 + j * 64 + g * 16);
            }
#pragma unroll
            for (int nb = 0; nb < 4; nb++) {
                int n = wc * 64 + nb * 16 + l15;
                bf[nb] = *(const bf16x8*)(BsB + n * 128 + j * 64 + g * 16);
            }
#pragma unroll
            for (int mb = 0; mb < 4; mb++)
#pragma unroll
                for (int nb = 0; nb < 4; nb++)
                    acc[mb][nb] = mfma_bf16(af[mb], bf[nb], acc[mb][nb]);
        }
    }
#pragma unroll
    for (int nb = 0; nb < 4; nb++) {
        int n_g = n0 + wc * 64 + nb * 16 + l15;
        float bs = bias[n_g];
#pragma unroll
        for (int mb = 0; mb < 4; mb++) {
            f32x4 v = acc[mb][nb];
#pragma unroll
            for (int r = 0; r < 4; r++) {
                int m_g = m0 + wr * 64 + mb * 16 + g * 4 + r;
                out[(size_t)m_g * 768 + n_g] = v[r] + bs;
            }
        }
    }
}

// ---------------------------------------------------------------------------
extern "C" void kernel_launch(void* const* d_in, const int* in_sizes, int n_in,
                              void* d_out, int out_size, void* d_ws, size_t ws_size,
                              hipStream_t stream) {
    (void)in_sizes; (void)n_in; (void)out_size; (void)ws_size;
    const float* x      = (const float*)d_in[0];
    const int*   mask   = (const int*)d_in[1];
    const float* w_qkv  = (const float*)d_in[2];
    const float* b_qkv  = (const float*)d_in[3];
    const float* w_proj = (const float*)d_in[4];
    const float* b_proj = (const float*)d_in[5];
    const float* pb     = (const float*)d_in[6];
    (void)pb;

    float* out  = (float*)d_out;
    float* attO = out + (size_t)Bb * Nn * Cc;   // 6,291,456

    char* ws = (char*)d_ws;
    unsigned short* xb     = (unsigned short*)(ws);             // 12,582,912 B
    unsigned short* wqkvt  = (unsigned short*)(ws + 12582912);  //  3,538,944 B
    unsigned short* wprojt = (unsigned short*)(ws + 16121856);  //  1,179,648 B
    unsigned short* qbuf   = (unsigned short*)(ws + 17301504);  // 12,582,912 B
    unsigned short* kbuf   = (unsigned short*)(ws + 29884416);  // 12,582,912 B
    unsigned short* vtb    = (unsigned short*)(ws + 42467328);  // 12,582,912 B
    unsigned short* ctx    = (unsigned short*)(ws + 55050240);  // 12,582,912 B  (total ~67.6 MB)

    k_cvt_bf16<<<6144, 256, 0, stream>>>(x, xb, 1572864);
    k_transpose_bf16<<<dim3(12, 36), 256, 0, stream>>>(w_qkv, wqkvt, 768, 2304);
    k_transpose_bf16<<<dim3(12, 12), 256, 0, stream>>>(w_proj, wprojt, 768, 768);
    k_gemm_qkv<<<dim3(64, 18), 256, 0, stream>>>(xb, wqkvt, b_qkv, qbuf, kbuf, vtb);
    k_attn<<<3072, 256, 0, stream>>>(qbuf, kbuf, vtb, mask, pb, attO, ctx);
    k_gemm_proj<<<dim3(64, 6), 256, 0, stream>>>(ctx, wprojt, b_proj, out);
}

// Round 10
// 451.963 us; speedup vs baseline: 1.0135x; 1.0135x over previous
//
#include <hip/hip_runtime.h>

// ---------------------------------------------------------------------------
// MultiHeadSelfAttention: x[4,2048,768] -> (out[4,2048,768], att[4,12,2048,2048])
// Pipeline: cvt/transpose -> QKV GEMM (bf16 MFMA) -> fused attention -> proj GEMM
// R10 = R9 with barrier-free Phase B: per-wave private LDS staging tile
// (intra-wave lgkmcnt ordering only), NT 256B-burst writeback. Barriers 18 -> 4.
// ---------------------------------------------------------------------------

typedef __attribute__((ext_vector_type(8)))  short          bf16x8;   // 8 bf16 (4 VGPR)
typedef __attribute__((ext_vector_type(4)))  float          f32x4;
typedef __attribute__((ext_vector_type(16))) float          f32x16;
typedef __attribute__((ext_vector_type(4)))  unsigned short us4;
typedef __attribute__((ext_vector_type(8)))  unsigned short us8;
typedef __attribute__((ext_vector_type(4)))  int            i32x4;
typedef __attribute__((ext_vector_type(4)))  unsigned int   u32x4;
typedef __attribute__((ext_vector_type(2)))  unsigned int   u32x2;

#define DEVFN static __device__ __forceinline__

enum : int { Bb = 4, Nn = 2048, Cc = 768, Hh = 12, Dd = 64, BH = 48, Mm = 8192, C3 = 2304 };

DEVFN unsigned short f2bf(float f) {
    unsigned int u = __float_as_uint(f);
    u = (u + 0x7fffu + ((u >> 16) & 1u)) >> 16;   // RNE
    return (unsigned short)u;
}

DEVFN void gload16(void* lds, const void* g) {
    __builtin_amdgcn_global_load_lds(
        (__attribute__((address_space(1))) void*)(g),
        (__attribute__((address_space(3))) void*)(lds), 16, 0, 0);
}

DEVFN f32x4 mfma_bf16(bf16x8 a, bf16x8 b, f32x4 c) {
    return __builtin_amdgcn_mfma_f32_16x16x32_bf16(a, b, c, 0, 0, 0);
}
DEVFN f32x16 mfma32(bf16x8 a, bf16x8 b, f32x16 c) {
    return __builtin_amdgcn_mfma_f32_32x32x16_bf16(a, b, c, 0, 0, 0);
}
DEVFN unsigned cvt_pk_bf16(float lo, float hi) {
    unsigned r;
    asm("v_cvt_pk_bf16_f32 %0, %1, %2" : "=v"(r) : "v"(lo), "v"(hi));
    return r;
}

// ---------------------------------------------------------------- cvt x->bf16
__global__ __launch_bounds__(256) void k_cvt_bf16(const float* __restrict__ in,
                                                  unsigned short* __restrict__ out, int n4) {
    int i = blockIdx.x * 256 + threadIdx.x;
    if (i < n4) {
        f32x4 v = ((const f32x4*)in)[i];
        us4 o;
        o[0] = f2bf(v[0]); o[1] = f2bf(v[1]); o[2] = f2bf(v[2]); o[3] = f2bf(v[3]);
        ((us4*)out)[i] = o;
    }
}

// ------------------------------------------------- transpose f32[R][C] -> bf16[C][R]
__global__ __launch_bounds__(256) void k_transpose_bf16(const float* __restrict__ in,
                                                        unsigned short* __restrict__ out,
                                                        int R, int Ccols) {
    __shared__ float t[64][65];
    int r0 = blockIdx.x * 64, c0 = blockIdx.y * 64;
    int tid = threadIdx.x;
#pragma unroll
    for (int i = 0; i < 16; i++) {
        int idx = i * 256 + tid; int lr = idx >> 6, lc = idx & 63;
        t[lr][lc] = in[(size_t)(r0 + lr) * Ccols + c0 + lc];
    }
    __syncthreads();
#pragma unroll
    for (int i = 0; i < 16; i++) {
        int idx = i * 256 + tid; int lc = idx >> 6, lr = idx & 63;
        out[(size_t)(c0 + lc) * R + r0 + lr] = f2bf(t[lr][lc]);
    }
}

// ------------------------------------------------------------- QKV GEMM
__global__ __launch_bounds__(256) void k_gemm_qkv(const unsigned short* __restrict__ A,
                                                  const unsigned short* __restrict__ Bt,
                                                  const float* __restrict__ bias,
                                                  unsigned short* __restrict__ qO,
                                                  unsigned short* __restrict__ kO,
                                                  unsigned short* __restrict__ vT) {
    __shared__ __align__(16) char smem[51200];
    char* AsB = smem;                 // [128][64] bf16 = 16384
    char* BsB = smem + 16384;         // [128][64] bf16 = 16384
    char* TsB = smem + 32768;         // epilogue staging, 18432 B
    int tid = threadIdx.x, lane = tid & 63, w = tid >> 6;
    int l15 = lane & 15, g = lane >> 4;
    int m0 = blockIdx.x * 128, n0 = blockIdx.y * 128;
    int wr = w >> 1, wc = w & 1;
    f32x4 acc[4][4] = {};

    for (int ks = 0; ks < 768; ks += 64) {
        __syncthreads();
#pragma unroll
        for (int i = 0; i < 4; i++) {
            int chunk = i * 256 + tid;
            int row = chunk >> 3, c8 = chunk & 7;
            gload16(AsB + chunk * 16, A + (size_t)(m0 + row) * 768 + ks + c8 * 8);
            gload16(BsB + chunk * 16, Bt + (size_t)(n0 + row) * 768 + ks + c8 * 8);
        }
        __syncthreads();
#pragma unroll
        for (int j = 0; j < 2; j++) {
            bf16x8 af[4], bf[4];
#pragma unroll
            for (int mb = 0; mb < 4; mb++) {
                int m = wr * 64 + mb * 16 + l15;
                af[mb] = *(const bf16x8*)(AsB + m * 128 + j * 64 + g * 16);
            }
#pragma unroll
            for (int nb = 0; nb < 4; nb++) {
                int n = wc * 64 + nb * 16 + l15;
                bf[nb] = *(const bf16x8*)(BsB + n * 128 + j * 64 + g * 16);
            }
#pragma unroll
            for (int mb = 0; mb < 4; mb++)
#pragma unroll
                for (int nb = 0; nb < 4; nb++)
                    acc[mb][nb] = mfma_bf16(af[mb], bf[nb], acc[mb][nb]);
        }
    }

    int which = n0 / 768;                 // 0=q 1=k 2=v (uniform per block)
    float bscale = (which == 0) ? 0.125f : 1.0f;
    unsigned short* Ts = (unsigned short*)TsB;

    for (int mh = 0; mh < 2; mh++) {      // two m-halves of 64 rows
        if (mh) __syncthreads();
        if (wr == mh) {
#pragma unroll
            for (int nb = 0; nb < 4; nb++) {
                int n_loc = wc * 64 + nb * 16 + l15;
                float bs = bias[n0 + n_loc];
#pragma unroll
                for (int mb = 0; mb < 4; mb++) {
                    f32x4 v = acc[mb][nb];
#pragma unroll
                    for (int r = 0; r < 4; r++) {
                        int m_loc = mb * 16 + g * 4 + r;
                        unsigned short bv = f2bf((v[r] + bs) * bscale);
                        if (which < 2)
                            Ts[m_loc * 136 + n_loc] = bv;      // [64][136]
                        else
                            Ts[n_loc * 72 + m_loc] = bv;       // [128][72] transposed
                    }
                }
            }
        }
        __syncthreads();
        if (which < 2) {
            int row = tid >> 2, hh = (tid >> 1) & 1, qq = tid & 1;
            int m_g = m0 + mh * 64 + row;
            int bI = m_g >> 11, tok = m_g & 2047;
            int h = ((n0 + hh * 64) - which * 768) >> 6;
            unsigned short* dst = (which == 0 ? qO : kO)
                                  + (size_t)((bI * 12 + h) * 2048 + tok) * 64 + qq * 32;
            const unsigned short* src = Ts + row * 136 + hh * 64 + qq * 32;
#pragma unroll
            for (int j = 0; j < 4; j++)
                *(us8*)(dst + j * 8) = *(const us8*)(src + j * 8);
        } else {
            int drow = tid >> 1, seg = tid & 1;
            int n_g = n0 + drow;
            int h = (n_g - 1536) >> 6, d = n_g & 63;
            int bI = m0 >> 11;
            unsigned short* dst = vT + (size_t)((bI * 12 + h) * 64 + d) * 2048
                                  + (m0 & 2047) + mh * 64 + seg * 32;
            const unsigned short* src = Ts + drow * 72 + seg * 32;
#pragma unroll
            for (int j = 0; j < 4; j++)
                *(us8*)(dst + j * 8) = *(const us8*)(src + j * 8);
        }
    }
}

// ------------------------------------------------------------- fused attention
// 3072 WGs (48 bh x 64 q-tiles, XCD-bijective) x 256 threads (4 waves).
// Phase A: barrier-free lsum + one LDS reduce (2 barriers).
// Phase B: BARRIER-FREE. Per-wave PRIVATE [32][67] f32 staging tile (stride 67
// -> all ds ops 2-way-max bank aliasing = free). Wave writes swapped quads,
// reads back row-major, NT-stores its own 64-col slice (256B full-line bursts).
// Intra-wave LDS ordering via compiler lgkmcnt; waves fully decoupled.
__global__ __launch_bounds__(256, 4) void k_attn(const unsigned short* __restrict__ qb,
                                                 const unsigned short* __restrict__ kbuf,
                                                 const unsigned short* __restrict__ vT,
                                                 const int* __restrict__ mask,
                                                 const float* __restrict__ pbias,
                                                 float* __restrict__ attO,
                                                 unsigned short* __restrict__ ctx) {
    // per-wave tiles: 4 x [32][67] f32 = 34304 B; overlay [4][32][65] fits inside.
    __shared__ __align__(16) char smem[34304 + 512 + 128];
    float* Ssm    = (float*)smem;
    float* l_part = (float*)(smem + 34304);   // [4][32]
    float* rowinv = (float*)(smem + 34816);   // [32]

    int tid = threadIdx.x, lane = tid & 63, w = tid >> 6;   // w = 0..3
    int l31 = lane & 31, hi = lane >> 5;
    int n = blockIdx.x;
    int xcd = n & 7, slot = n >> 3;
    int bh = xcd * 6 + (slot >> 6), qt = slot & 63;
    int b = bh / 12, h = bh - b * 12;
    int q0 = qt * 32;
    (void)pbias;

    const unsigned short* kbase = kbuf + (size_t)bh * 2048 * 64;
    const unsigned short* vbase = vT + (size_t)bh * 64 * 2048;
    const int* mbase = mask + b * 2048 + hi * 4;

    bf16x8 qf0, qf1, qf2, qf3;
    {
        const unsigned short* qp = qb + (size_t)(bh * 2048 + q0 + l31) * 64 + hi * 8;
        qf0 = *(const bf16x8*)(qp);
        qf1 = *(const bf16x8*)(qp + 16);
        qf2 = *(const bf16x8*)(qp + 32);
        qf3 = *(const bf16x8*)(qp + 48);
    }
    const unsigned short* kp = kbase + (size_t)l31 * 64 + hi * 8;
    const unsigned short* vp = vbase + (size_t)l31 * 2048 + hi * 8;

    // ---------------- Phase A: lsum over wave's k-slice ----------------
    float lsum = 0.f;
#pragma unroll 2
    for (int t = 0; t < 16; t++) {
        int k0 = w * 512 + t * 32;
        const unsigned short* kpt = kp + (size_t)k0 * 64;
        bf16x8 kf0 = *(const bf16x8*)(kpt);
        bf16x8 kf1 = *(const bf16x8*)(kpt + 16);
        bf16x8 kf2 = *(const bf16x8*)(kpt + 32);
        bf16x8 kf3 = *(const bf16x8*)(kpt + 48);
        i32x4 m0 = *(const i32x4*)(mbase + k0);
        i32x4 m1 = *(const i32x4*)(mbase + k0 + 8);
        i32x4 m2 = *(const i32x4*)(mbase + k0 + 16);
        i32x4 m3 = *(const i32x4*)(mbase + k0 + 24);
        f32x16 s = {};
        s = mfma32(kf0, qf0, s);
        s = mfma32(kf1, qf1, s);
        s = mfma32(kf2, qf2, s);
        s = mfma32(kf3, qf3, s);
#pragma unroll
        for (int i = 0; i < 4; i++) lsum += m0[i] ? __expf(fminf(s[i], 75.f)) : 0.f;
#pragma unroll
        for (int i = 0; i < 4; i++) lsum += m1[i] ? __expf(fminf(s[4 + i], 75.f)) : 0.f;
#pragma unroll
        for (int i = 0; i < 4; i++) lsum += m2[i] ? __expf(fminf(s[8 + i], 75.f)) : 0.f;
#pragma unroll
        for (int i = 0; i < 4; i++) lsum += m3[i] ? __expf(fminf(s[12 + i], 75.f)) : 0.f;
    }
    lsum += __shfl_xor(lsum, 32, 64);
    if (hi == 0) l_part[w * 32 + l31] = lsum;
    __syncthreads();
    if (tid < 32)
        rowinv[tid] = 1.0f / (l_part[tid] + l_part[32 + tid] + l_part[64 + tid] + l_part[96 + tid]);
    __syncthreads();
    float rinv = rowinv[l31];

    // ---------------- Phase B: barrier-free, per-wave private staging ----------------
    float* myS = Ssm + w * 2144;               // [32][67] f32, private to wave w
    float* attW = attO + (size_t)(bh * 2048 + q0) * 2048 + w * 64;  // + row*2048 + p*256

    f32x16 c0 = {}, c1 = {};
    for (int p = 0; p < 8; p++) {
#pragma unroll
        for (int t = 0; t < 2; t++) {
            int k0 = p * 256 + w * 64 + t * 32;
            const unsigned short* kpt = kp + (size_t)k0 * 64;
            bf16x8 kf0 = *(const bf16x8*)(kpt);
            bf16x8 kf1 = *(const bf16x8*)(kpt + 16);
            bf16x8 kf2 = *(const bf16x8*)(kpt + 32);
            bf16x8 kf3 = *(const bf16x8*)(kpt + 48);
            bf16x8 vf00 = *(const bf16x8*)(vp + k0);
            bf16x8 vf01 = *(const bf16x8*)(vp + k0 + 16);
            bf16x8 vf10 = *(const bf16x8*)(vp + 65536 + k0);
            bf16x8 vf11 = *(const bf16x8*)(vp + 65536 + k0 + 16);
            i32x4 m0 = *(const i32x4*)(mbase + k0);
            i32x4 m1 = *(const i32x4*)(mbase + k0 + 8);
            i32x4 m2 = *(const i32x4*)(mbase + k0 + 16);
            i32x4 m3 = *(const i32x4*)(mbase + k0 + 24);
            f32x16 s = {};
            s = mfma32(kf0, qf0, s);
            s = mfma32(kf1, qf1, s);
            s = mfma32(kf2, qf2, s);
            s = mfma32(kf3, qf3, s);

            float* srow = myS + l31 * 67 + t * 32 + 4 * hi;   // quads at +8j
            unsigned pk00, pk01, pk10, pk11, pk20, pk21, pk30, pk31;
            {
                float a0 = (m0[0] ? __expf(fminf(s[0], 75.f)) : 0.f) * rinv;
                float a1 = (m0[1] ? __expf(fminf(s[1], 75.f)) : 0.f) * rinv;
                float a2 = (m0[2] ? __expf(fminf(s[2], 75.f)) : 0.f) * rinv;
                float a3 = (m0[3] ? __expf(fminf(s[3], 75.f)) : 0.f) * rinv;
                f32x4 av = {a0, a1, a2, a3};
                *(f32x4*)(srow) = av;
                pk00 = cvt_pk_bf16(a0, a1); pk01 = cvt_pk_bf16(a2, a3);
            }
            {
                float a0 = (m1[0] ? __expf(fminf(s[4], 75.f)) : 0.f) * rinv;
                float a1 = (m1[1] ? __expf(fminf(s[5], 75.f)) : 0.f) * rinv;
                float a2 = (m1[2] ? __expf(fminf(s[6], 75.f)) : 0.f) * rinv;
                float a3 = (m1[3] ? __expf(fminf(s[7], 75.f)) : 0.f) * rinv;
                f32x4 av = {a0, a1, a2, a3};
                *(f32x4*)(srow + 8) = av;
                pk10 = cvt_pk_bf16(a0, a1); pk11 = cvt_pk_bf16(a2, a3);
            }
            {
                float a0 = (m2[0] ? __expf(fminf(s[8], 75.f)) : 0.f) * rinv;
                float a1 = (m2[1] ? __expf(fminf(s[9], 75.f)) : 0.f) * rinv;
                float a2 = (m2[2] ? __expf(fminf(s[10], 75.f)) : 0.f) * rinv;
                float a3 = (m2[3] ? __expf(fminf(s[11], 75.f)) : 0.f) * rinv;
                f32x4 av = {a0, a1, a2, a3};
                *(f32x4*)(srow + 16) = av;
                pk20 = cvt_pk_bf16(a0, a1); pk21 = cvt_pk_bf16(a2, a3);
            }
            {
                float a0 = (m3[0] ? __expf(fminf(s[12], 75.f)) : 0.f) * rinv;
                float a1 = (m3[1] ? __expf(fminf(s[13], 75.f)) : 0.f) * rinv;
                float a2 = (m3[2] ? __expf(fminf(s[14], 75.f)) : 0.f) * rinv;
                float a3 = (m3[3] ? __expf(fminf(s[15], 75.f)) : 0.f) * rinv;
                f32x4 av = {a0, a1, a2, a3};
                *(f32x4*)(srow + 24) = av;
                pk30 = cvt_pk_bf16(a0, a1); pk31 = cvt_pk_bf16(a2, a3);
            }
            {
                u32x2 sA = __builtin_amdgcn_permlane32_swap(pk00, pk10, false, false);
                u32x2 sB = __builtin_amdgcn_permlane32_swap(pk01, pk11, false, false);
                u32x4 bi = {sA[0], sB[0], sA[1], sB[1]};
                bf16x8 pf = __builtin_bit_cast(bf16x8, bi);
                c0 = mfma32(vf00, pf, c0);
                c1 = mfma32(vf10, pf, c1);
            }
            {
                u32x2 sA = __builtin_amdgcn_permlane32_swap(pk20, pk30, false, false);
                u32x2 sB = __builtin_amdgcn_permlane32_swap(pk21, pk31, false, false);
                u32x4 bi = {sA[0], sB[0], sA[1], sB[1]};
                bf16x8 pf = __builtin_bit_cast(bf16x8, bi);
                c0 = mfma32(vf01, pf, c0);
                c1 = mfma32(vf11, pf, c1);
            }
        }
        // writeback (no barrier): 8 steps x 4 rows, 256B full-line NT bursts
        {
            int rsub = lane >> 4, c16 = lane & 15;
#pragma unroll
            for (int st = 0; st < 8; st++) {
                int row = st * 4 + rsub;
                f32x4 v = *(const f32x4*)(myS + row * 67 + c16 * 4);
                __builtin_nontemporal_store(v,
                    (f32x4*)(attW + (size_t)row * 2048 + p * 256 + c16 * 4));
            }
        }
    }

    // ---------------- ctx: two-step wave-partial reduction ----------------
    __syncthreads();   // overlay below spans other waves' private tiles
    {
        float* cw = Ssm + w * 2080 + l31 * 65;   // [4][32][65] overlay
#pragma unroll
        for (int r = 0; r < 16; r++) {
            int d = (r & 3) + 8 * (r >> 2) + 4 * hi;
            cw[d] = c0[r];
            cw[d + 32] = c1[r];
        }
    }
    __syncthreads();
    {
        int q = tid >> 3, d0 = (tid & 7) * 8;
        float a[8];
#pragma unroll
        for (int j = 0; j < 8; j++) a[j] = 0.f;
#pragma unroll
        for (int w2 = 0; w2 < 4; w2++) {
            const float* cw = Ssm + w2 * 2080 + q * 65 + d0;
#pragma unroll
            for (int j = 0; j < 8; j++) a[j] += cw[j];
        }
        us4 o0, o1;
        o0[0] = f2bf(a[0]); o0[1] = f2bf(a[1]); o0[2] = f2bf(a[2]); o0[3] = f2bf(a[3]);
        o1[0] = f2bf(a[4]); o1[1] = f2bf(a[5]); o1[2] = f2bf(a[6]); o1[3] = f2bf(a[7]);
        unsigned short* cp = ctx + (size_t)(b * 2048 + q0 + q) * 768 + h * 64 + d0;
        *(us4*)(cp) = o0;
        *(us4*)(cp + 4) = o1;
    }
}

// ------------------------------------------------------------- proj GEMM
__global__ __launch_bounds__(256) void k_gemm_proj(const unsigned short* __restrict__ A,
                                                   const unsigned short* __restrict__ Bt,
                                                   const float* __restrict__ bias,
                                                   float* __restrict__ out) {
    __shared__ __align__(16) unsigned short As[128 * 64];
    __shared__ __align__(16) unsigned short Bs[128 * 64];
    char* AsB = (char*)As; char* BsB = (char*)Bs;
    int tid = threadIdx.x, lane = tid & 63, w = tid >> 6;
    int l15 = lane & 15, g = lane >> 4;
    int m0 = blockIdx.x * 128, n0 = blockIdx.y * 128;
    int wr = w >> 1, wc = w & 1;
    f32x4 acc[4][4] = {};

    for (int ks = 0; ks < 768; ks += 64) {
        __syncthreads();
#pragma unroll
        for (int i = 0; i < 4; i++) {
            int chunk = i * 256 + tid;
            int row = chunk >> 3, c8 = chunk & 7;
            gload16(AsB + chunk * 16, A + (size_t)(m0 + row) * 768 + ks + c8 * 8);
            gload16(BsB + chunk * 16, Bt + (size_t)(n0 + row) * 768 + ks + c8 * 8);
        }
        __syncthreads();
#pragma unroll
        for (int j = 0; j < 2; j++) {
            bf16x8 af[4], bf[4];
#pragma unroll
            for (int mb = 0; mb < 4; mb++) {
                int m = wr * 64 + mb * 16 + l15;
                af[mb] = *(const bf16x8*)(AsB + m * 128 + j * 64 + g * 16);
            }
#pragma unroll
            for (int nb = 0; nb < 4; nb++) {
                int n = wc * 64 + nb * 16 + l15;
                bf[nb] = *(const bf16x8*)(BsB + n * 128 + j * 64 + g * 16);
            }
#pragma unroll
            for (int mb = 0; mb < 4; mb++)
#pragma unroll
                for (int nb = 0; nb < 4; nb++)
                    acc[mb][nb] = mfma_bf16(af[mb], bf[nb], acc[mb][nb]);
        }
    }
#pragma unroll
    for (int nb = 0; nb < 4; nb++) {
        int n_g = n0 + wc * 64 + nb * 16 + l15;
        float bs = bias[n_g];
#pragma unroll
        for (int mb = 0; mb < 4; mb++) {
            f32x4 v = acc[mb][nb];
#pragma unroll
            for (int r = 0; r < 4; r++) {
                int m_g = m0 + wr * 64 + mb * 16 + g * 4 + r;
                out[(size_t)m_g * 768 + n_g] = v[r] + bs;
            }
        }
    }
}

// ---------------------------------------------------------------------------
extern "C" void kernel_launch(void* const* d_in, const int* in_sizes, int n_in,
                              void* d_out, int out_size, void* d_ws, size_t ws_size,
                              hipStream_t stream) {
    (void)in_sizes; (void)n_in; (void)out_size; (void)ws_size;
    const float* x      = (const float*)d_in[0];
    const int*   mask   = (const int*)d_in[1];
    const float* w_qkv  = (const float*)d_in[2];
    const float* b_qkv  = (const float*)d_in[3];
    const float* w_proj = (const float*)d_in[4];
    const float* b_proj = (const float*)d_in[5];
    const float* pb     = (const float*)d_in[6];
    (void)pb;

    float* out  = (float*)d_out;
    float* attO = out + (size_t)Bb * Nn * Cc;   // 6,291,456

    char* ws = (char*)d_ws;
    unsigned short* xb     = (unsigned short*)(ws);             // 12,582,912 B
    unsigned short* wqkvt  = (unsigned short*)(ws + 12582912);  //  3,538,944 B
    unsigned short* wprojt = (unsigned short*)(ws + 16121856);  //  1,179,648 B
    unsigned short* qbuf   = (unsigned short*)(ws + 17301504);  // 12,582,912 B
    unsigned short* kbuf   = (unsigned short*)(ws + 29884416);  // 12,582,912 B
    unsigned short* vtb    = (unsigned short*)(ws + 42467328);  // 12,582,912 B
    unsigned short* ctx    = (unsigned short*)(ws + 55050240);  // 12,582,912 B  (total ~67.6 MB)

    k_cvt_bf16<<<6144, 256, 0, stream>>>(x, xb, 1572864);
    k_transpose_bf16<<<dim3(12, 36), 256, 0, stream>>>(w_qkv, wqkvt, 768, 2304);
    k_transpose_bf16<<<dim3(12, 12), 256, 0, stream>>>(w_proj, wprojt, 768, 768);
    k_gemm_qkv<<<dim3(64, 18), 256, 0, stream>>>(xb, wqkvt, b_qkv, qbuf, kbuf, vtb);
    k_attn<<<3072, 256, 0, stream>>>(qbuf, kbuf, vtb, mask, pb, attO, ctx);
    k_gemm_proj<<<dim3(64, 6), 256, 0, stream>>>(ctx, wprojt, b_proj, out);
}

// Round 11
// 420.700 us; speedup vs baseline: 1.0888x; 1.0743x over previous
//
#include <hip/hip_runtime.h>

// ---------------------------------------------------------------------------
// MultiHeadSelfAttention: x[4,2048,768] -> (out[4,2048,768], att[4,12,2048,2048])
// Pipeline: cvt/transpose -> QKV GEMM -> maskbits -> fused attention -> proj GEMM
// R11 = R10 + register-double-buffered K/V with loads issued BEFORE the NT store
// burst (vmcnt FIFO: loads older than stores don't wait on store completion),
// masks via packed bitmask (scalar/lgkm path, zero vmem in the compute body).
// ---------------------------------------------------------------------------

typedef __attribute__((ext_vector_type(8)))  short          bf16x8;   // 8 bf16 (4 VGPR)
typedef __attribute__((ext_vector_type(4)))  float          f32x4;
typedef __attribute__((ext_vector_type(16))) float          f32x16;
typedef __attribute__((ext_vector_type(4)))  unsigned short us4;
typedef __attribute__((ext_vector_type(8)))  unsigned short us8;
typedef __attribute__((ext_vector_type(4)))  int            i32x4;
typedef __attribute__((ext_vector_type(4)))  unsigned int   u32x4;
typedef __attribute__((ext_vector_type(2)))  unsigned int   u32x2;

#define DEVFN static __device__ __forceinline__

enum : int { Bb = 4, Nn = 2048, Cc = 768, Hh = 12, Dd = 64, BH = 48, Mm = 8192, C3 = 2304 };

DEVFN unsigned short f2bf(float f) {
    unsigned int u = __float_as_uint(f);
    u = (u + 0x7fffu + ((u >> 16) & 1u)) >> 16;   // RNE
    return (unsigned short)u;
}

DEVFN void gload16(void* lds, const void* g) {
    __builtin_amdgcn_global_load_lds(
        (__attribute__((address_space(1))) void*)(g),
        (__attribute__((address_space(3))) void*)(lds), 16, 0, 0);
}

DEVFN f32x4 mfma_bf16(bf16x8 a, bf16x8 b, f32x4 c) {
    return __builtin_amdgcn_mfma_f32_16x16x32_bf16(a, b, c, 0, 0, 0);
}
DEVFN f32x16 mfma32(bf16x8 a, bf16x8 b, f32x16 c) {
    return __builtin_amdgcn_mfma_f32_32x32x16_bf16(a, b, c, 0, 0, 0);
}
DEVFN unsigned cvt_pk_bf16(float lo, float hi) {
    unsigned r;
    asm("v_cvt_pk_bf16_f32 %0, %1, %2" : "=v"(r) : "v"(lo), "v"(hi));
    return r;
}

// ---------------------------------------------------------------- cvt x->bf16
__global__ __launch_bounds__(256) void k_cvt_bf16(const float* __restrict__ in,
                                                  unsigned short* __restrict__ out, int n4) {
    int i = blockIdx.x * 256 + threadIdx.x;
    if (i < n4) {
        f32x4 v = ((const f32x4*)in)[i];
        us4 o;
        o[0] = f2bf(v[0]); o[1] = f2bf(v[1]); o[2] = f2bf(v[2]); o[3] = f2bf(v[3]);
        ((us4*)out)[i] = o;
    }
}

// ------------------------------------------------- transpose f32[R][C] -> bf16[C][R]
__global__ __launch_bounds__(256) void k_transpose_bf16(const float* __restrict__ in,
                                                        unsigned short* __restrict__ out,
                                                        int R, int Ccols) {
    __shared__ float t[64][65];
    int r0 = blockIdx.x * 64, c0 = blockIdx.y * 64;
    int tid = threadIdx.x;
#pragma unroll
    for (int i = 0; i < 16; i++) {
        int idx = i * 256 + tid; int lr = idx >> 6, lc = idx & 63;
        t[lr][lc] = in[(size_t)(r0 + lr) * Ccols + c0 + lc];
    }
    __syncthreads();
#pragma unroll
    for (int i = 0; i < 16; i++) {
        int idx = i * 256 + tid; int lc = idx >> 6, lr = idx & 63;
        out[(size_t)(c0 + lc) * R + r0 + lr] = f2bf(t[lr][lc]);
    }
}

// ------------------------------------------------- mask -> bitmask (4 x 64 u32)
__global__ __launch_bounds__(256) void k_maskbits(const int* __restrict__ mask,
                                                  unsigned char* __restrict__ mb) {
    int b = blockIdx.x, t = threadIdx.x;
    const int* mp = mask + b * 2048 + t * 8;
    unsigned byte = 0;
#pragma unroll
    for (int i = 0; i < 8; i++) byte |= (mp[i] ? 1u : 0u) << i;
    mb[b * 256 + t] = (unsigned char)byte;
}

// ------------------------------------------------------------- QKV GEMM
__global__ __launch_bounds__(256) void k_gemm_qkv(const unsigned short* __restrict__ A,
                                                  const unsigned short* __restrict__ Bt,
                                                  const float* __restrict__ bias,
                                                  unsigned short* __restrict__ qO,
                                                  unsigned short* __restrict__ kO,
                                                  unsigned short* __restrict__ vT) {
    __shared__ __align__(16) char smem[51200];
    char* AsB = smem;
    char* BsB = smem + 16384;
    char* TsB = smem + 32768;
    int tid = threadIdx.x, lane = tid & 63, w = tid >> 6;
    int l15 = lane & 15, g = lane >> 4;
    int m0 = blockIdx.x * 128, n0 = blockIdx.y * 128;
    int wr = w >> 1, wc = w & 1;
    f32x4 acc[4][4] = {};

    for (int ks = 0; ks < 768; ks += 64) {
        __syncthreads();
#pragma unroll
        for (int i = 0; i < 4; i++) {
            int chunk = i * 256 + tid;
            int row = chunk >> 3, c8 = chunk & 7;
            gload16(AsB + chunk * 16, A + (size_t)(m0 + row) * 768 + ks + c8 * 8);
            gload16(BsB + chunk * 16, Bt + (size_t)(n0 + row) * 768 + ks + c8 * 8);
        }
        __syncthreads();
#pragma unroll
        for (int j = 0; j < 2; j++) {
            bf16x8 af[4], bf[4];
#pragma unroll
            for (int mb = 0; mb < 4; mb++) {
                int m = wr * 64 + mb * 16 + l15;
                af[mb] = *(const bf16x8*)(AsB + m * 128 + j * 64 + g * 16);
            }
#pragma unroll
            for (int nb = 0; nb < 4; nb++) {
                int n = wc * 64 + nb * 16 + l15;
                bf[nb] = *(const bf16x8*)(BsB + n * 128 + j * 64 + g * 16);
            }
#pragma unroll
            for (int mb = 0; mb < 4; mb++)
#pragma unroll
                for (int nb = 0; nb < 4; nb++)
                    acc[mb][nb] = mfma_bf16(af[mb], bf[nb], acc[mb][nb]);
        }
    }

    int which = n0 / 768;
    float bscale = (which == 0) ? 0.125f : 1.0f;
    unsigned short* Ts = (unsigned short*)TsB;

    for (int mh = 0; mh < 2; mh++) {
        if (mh) __syncthreads();
        if (wr == mh) {
#pragma unroll
            for (int nb = 0; nb < 4; nb++) {
                int n_loc = wc * 64 + nb * 16 + l15;
                float bs = bias[n0 + n_loc];
#pragma unroll
                for (int mb = 0; mb < 4; mb++) {
                    f32x4 v = acc[mb][nb];
#pragma unroll
                    for (int r = 0; r < 4; r++) {
                        int m_loc = mb * 16 + g * 4 + r;
                        unsigned short bv = f2bf((v[r] + bs) * bscale);
                        if (which < 2)
                            Ts[m_loc * 136 + n_loc] = bv;
                        else
                            Ts[n_loc * 72 + m_loc] = bv;
                    }
                }
            }
        }
        __syncthreads();
        if (which < 2) {
            int row = tid >> 2, hh = (tid >> 1) & 1, qq = tid & 1;
            int m_g = m0 + mh * 64 + row;
            int bI = m_g >> 11, tok = m_g & 2047;
            int h = ((n0 + hh * 64) - which * 768) >> 6;
            unsigned short* dst = (which == 0 ? qO : kO)
                                  + (size_t)((bI * 12 + h) * 2048 + tok) * 64 + qq * 32;
            const unsigned short* src = Ts + row * 136 + hh * 64 + qq * 32;
#pragma unroll
            for (int j = 0; j < 4; j++)
                *(us8*)(dst + j * 8) = *(const us8*)(src + j * 8);
        } else {
            int drow = tid >> 1, seg = tid & 1;
            int n_g = n0 + drow;
            int h = (n_g - 1536) >> 6, d = n_g & 63;
            int bI = m0 >> 11;
            unsigned short* dst = vT + (size_t)((bI * 12 + h) * 64 + d) * 2048
                                  + (m0 & 2047) + mh * 64 + seg * 32;
            const unsigned short* src = Ts + drow * 72 + seg * 32;
#pragma unroll
            for (int j = 0; j < 4; j++)
                *(us8*)(dst + j * 8) = *(const us8*)(src + j * 8);
        }
    }
}

// ------------------------------------------------------------- fused attention
#define LOADKV(K0, Kf0, Kf1, Kf2, Kf3, Vf0, Vf1, Vf2, Vf3)            \
    {                                                                  \
        const unsigned short* kpt_ = kp + (size_t)(K0) * 64;           \
        Kf0 = *(const bf16x8*)(kpt_);                                  \
        Kf1 = *(const bf16x8*)(kpt_ + 16);                             \
        Kf2 = *(const bf16x8*)(kpt_ + 32);                             \
        Kf3 = *(const bf16x8*)(kpt_ + 48);                             \
        Vf0 = *(const bf16x8*)(vp + (K0));                             \
        Vf1 = *(const bf16x8*)(vp + (K0) + 16);                        \
        Vf2 = *(const bf16x8*)(vp + 65536 + (K0));                     \
        Vf3 = *(const bf16x8*)(vp + 65536 + (K0) + 16);                \
    }

#define BQUAD(J, S0, S1, S2, S3, MW, SROW, PKA, PKB)                                   \
    {                                                                                   \
        float e0 = __expf(fminf(S0, 75.f)) * rinv;                                      \
        float e1 = __expf(fminf(S1, 75.f)) * rinv;                                      \
        float e2 = __expf(fminf(S2, 75.f)) * rinv;                                      \
        float e3 = __expf(fminf(S3, 75.f)) * rinv;                                      \
        float a0 = ((MW >> (shv + 8 * (J) + 0)) & 1) ? e0 : 0.f;                        \
        float a1 = ((MW >> (shv + 8 * (J) + 1)) & 1) ? e1 : 0.f;                        \
        float a2 = ((MW >> (shv + 8 * (J) + 2)) & 1) ? e2 : 0.f;                        \
        float a3 = ((MW >> (shv + 8 * (J) + 3)) & 1) ? e3 : 0.f;                        \
        f32x4 av = {a0, a1, a2, a3};                                                    \
        *(f32x4*)((SROW) + 8 * (J)) = av;                                               \
        PKA = cvt_pk_bf16(a0, a1);                                                      \
        PKB = cvt_pk_bf16(a2, a3);                                                      \
    }

#define BTILE(Kf0, Kf1, Kf2, Kf3, Vf0, Vf1, Vf2, Vf3, MW, TT)                           \
    {                                                                                   \
        f32x16 s = {};                                                                  \
        s = mfma32(Kf0, qf0, s);                                                        \
        s = mfma32(Kf1, qf1, s);                                                        \
        s = mfma32(Kf2, qf2, s);                                                        \
        s = mfma32(Kf3, qf3, s);                                                        \
        float* srow = myS + l31 * 67 + (TT) * 32 + 4 * hi;                              \
        unsigned pk00, pk01, pk10, pk11, pk20, pk21, pk30, pk31;                        \
        BQUAD(0, s[0], s[1], s[2], s[3], MW, srow, pk00, pk01)                          \
        BQUAD(1, s[4], s[5], s[6], s[7], MW, srow, pk10, pk11)                          \
        BQUAD(2, s[8], s[9], s[10], s[11], MW, srow, pk20, pk21)                        \
        BQUAD(3, s[12], s[13], s[14], s[15], MW, srow, pk30, pk31)                      \
        {                                                                               \
            u32x2 sA = __builtin_amdgcn_permlane32_swap(pk00, pk10, false, false);      \
            u32x2 sB = __builtin_amdgcn_permlane32_swap(pk01, pk11, false, false);      \
            u32x4 bi = {sA[0], sB[0], sA[1], sB[1]};                                    \
            bf16x8 pf = __builtin_bit_cast(bf16x8, bi);                                 \
            c0 = mfma32(Vf0, pf, c0);                                                   \
            c1 = mfma32(Vf2, pf, c1);                                                   \
        }                                                                               \
        {                                                                               \
            u32x2 sA = __builtin_amdgcn_permlane32_swap(pk20, pk30, false, false);      \
            u32x2 sB = __builtin_amdgcn_permlane32_swap(pk21, pk31, false, false);      \
            u32x4 bi = {sA[0], sB[0], sA[1], sB[1]};                                    \
            bf16x8 pf = __builtin_bit_cast(bf16x8, bi);                                 \
            c0 = mfma32(Vf1, pf, c0);                                                   \
            c1 = mfma32(Vf3, pf, c1);                                                   \
        }                                                                               \
    }

// 3072 WGs (48 bh x 64 q-tiles, XCD-bijective) x 256 threads (4 waves).
// Phase A: barrier-free lsum + one LDS reduce. Masks via packed bitmask
// (wave-uniform scalar word per 32-k tile; no vector mask loads anywhere).
// Phase B: per-wave private LDS staging (no barriers); K/V register
// double-buffered with next-phase loads issued BEFORE the NT store burst, so
// load-waits stop at vmcnt(#stores) instead of draining stores to HBM.
__global__ __launch_bounds__(256, 3) void k_attn(const unsigned short* __restrict__ qb,
                                                 const unsigned short* __restrict__ kbuf,
                                                 const unsigned short* __restrict__ vT,
                                                 const unsigned* __restrict__ maskbits,
                                                 float* __restrict__ attO,
                                                 unsigned short* __restrict__ ctx) {
    __shared__ __align__(16) char smem[34304 + 512 + 128];
    float* Ssm    = (float*)smem;
    float* l_part = (float*)(smem + 34304);   // [4][32]
    float* rowinv = (float*)(smem + 34816);   // [32]

    int tid = threadIdx.x, lane = tid & 63, w = tid >> 6;   // w = 0..3
    int l31 = lane & 31, hi = lane >> 5;
    int n = blockIdx.x;
    int xcd = n & 7, slot = n >> 3;
    int bh = xcd * 6 + (slot >> 6), qt = slot & 63;
    int b = bh / 12, h = bh - b * 12;
    int q0 = qt * 32;
    int shv = 4 * hi;

    const unsigned short* kbase = kbuf + (size_t)bh * 2048 * 64;
    const unsigned short* vbase = vT + (size_t)bh * 64 * 2048;
    const unsigned* mwrds = maskbits + b * 64;

    bf16x8 qf0, qf1, qf2, qf3;
    {
        const unsigned short* qp = qb + (size_t)(bh * 2048 + q0 + l31) * 64 + hi * 8;
        qf0 = *(const bf16x8*)(qp);
        qf1 = *(const bf16x8*)(qp + 16);
        qf2 = *(const bf16x8*)(qp + 32);
        qf3 = *(const bf16x8*)(qp + 48);
    }
    const unsigned short* kp = kbase + (size_t)l31 * 64 + hi * 8;
    const unsigned short* vp = vbase + (size_t)l31 * 2048 + hi * 8;

    // ---------------- Phase A: lsum over wave's k-slice ----------------
    float lsum = 0.f;
#pragma unroll 2
    for (int t = 0; t < 16; t++) {
        int k0 = w * 512 + t * 32;
        const unsigned short* kpt = kp + (size_t)k0 * 64;
        bf16x8 kf0 = *(const bf16x8*)(kpt);
        bf16x8 kf1 = *(const bf16x8*)(kpt + 16);
        bf16x8 kf2 = *(const bf16x8*)(kpt + 32);
        bf16x8 kf3 = *(const bf16x8*)(kpt + 48);
        unsigned mw = mwrds[k0 >> 5];
        f32x16 s = {};
        s = mfma32(kf0, qf0, s);
        s = mfma32(kf1, qf1, s);
        s = mfma32(kf2, qf2, s);
        s = mfma32(kf3, qf3, s);
#pragma unroll
        for (int r = 0; r < 16; r++) {
            float e = __expf(fminf(s[r], 75.f));
            lsum += ((mw >> (shv + (r & 3) + 8 * (r >> 2))) & 1) ? e : 0.f;
        }
    }
    lsum += __shfl_xor(lsum, 32, 64);
    if (hi == 0) l_part[w * 32 + l31] = lsum;
    __syncthreads();
    if (tid < 32)
        rowinv[tid] = 1.0f / (l_part[tid] + l_part[32 + tid] + l_part[64 + tid] + l_part[96 + tid]);
    __syncthreads();
    float rinv = rowinv[l31];

    // ---------------- Phase B: pipelined, barrier-free ----------------
    float* myS = Ssm + w * 2144;               // [32][67] f32, private to wave w
    float* attW = attO + (size_t)(bh * 2048 + q0) * 2048 + w * 64;

    bf16x8 ka0, ka1, ka2, ka3, va0, va1, va2, va3;
    bf16x8 kb0, kb1, kb2, kb3, vb0, vb1, vb2, vb3;
    unsigned mwA, mwB;
    {
        int k0 = w * 64;
        LOADKV(k0, ka0, ka1, ka2, ka3, va0, va1, va2, va3);
        mwA = mwrds[k0 >> 5];
        LOADKV(k0 + 32, kb0, kb1, kb2, kb3, vb0, vb1, vb2, vb3);
        mwB = mwrds[(k0 + 32) >> 5];
    }

    f32x16 c0 = {}, c1 = {};
    for (int p = 0; p < 8; p++) {
        BTILE(ka0, ka1, ka2, ka3, va0, va1, va2, va3, mwA, 0);
        BTILE(kb0, kb1, kb2, kb3, vb0, vb1, vb2, vb3, mwB, 1);
        if (p < 7) {   // prefetch next phase BEFORE this phase's stores
            int nk = (p + 1) * 256 + w * 64;
            LOADKV(nk, ka0, ka1, ka2, ka3, va0, va1, va2, va3);
            mwA = mwrds[nk >> 5];
            LOADKV(nk + 32, kb0, kb1, kb2, kb3, vb0, vb1, vb2, vb3);
            mwB = mwrds[(nk + 32) >> 5];
        }
        asm volatile("" ::: "memory");   // pin: loads above, stores below
        {
            int rsub = lane >> 4, c16 = lane & 15;
#pragma unroll
            for (int st = 0; st < 8; st++) {
                int row = st * 4 + rsub;
                f32x4 v = *(const f32x4*)(myS + row * 67 + c16 * 4);
                __builtin_nontemporal_store(v,
                    (f32x4*)(attW + (size_t)row * 2048 + p * 256 + c16 * 4));
            }
        }
    }

    // ---------------- ctx: two-step wave-partial reduction ----------------
    __syncthreads();
    {
        float* cw = Ssm + w * 2080 + l31 * 65;   // [4][32][65] overlay
#pragma unroll
        for (int r = 0; r < 16; r++) {
            int d = (r & 3) + 8 * (r >> 2) + 4 * hi;
            cw[d] = c0[r];
            cw[d + 32] = c1[r];
        }
    }
    __syncthreads();
    {
        int q = tid >> 3, d0 = (tid & 7) * 8;
        float a[8];
#pragma unroll
        for (int j = 0; j < 8; j++) a[j] = 0.f;
#pragma unroll
        for (int w2 = 0; w2 < 4; w2++) {
            const float* cw = Ssm + w2 * 2080 + q * 65 + d0;
#pragma unroll
            for (int j = 0; j < 8; j++) a[j] += cw[j];
        }
        us4 o0, o1;
        o0[0] = f2bf(a[0]); o0[1] = f2bf(a[1]); o0[2] = f2bf(a[2]); o0[3] = f2bf(a[3]);
        o1[0] = f2bf(a[4]); o1[1] = f2bf(a[5]); o1[2] = f2bf(a[6]); o1[3] = f2bf(a[7]);
        unsigned short* cp = ctx + (size_t)(b * 2048 + q0 + q) * 768 + h * 64 + d0;
        *(us4*)(cp) = o0;
        *(us4*)(cp + 4) = o1;
    }
}

// ------------------------------------------------------------- proj GEMM
__global__ __launch_bounds__(256) void k_gemm_proj(const unsigned short* __restrict__ A,
                                                   const unsigned short* __restrict__ Bt,
                                                   const float* __restrict__ bias,
                                                   float* __restrict__ out) {
    __shared__ __align__(16) unsigned short As[128 * 64];
    __shared__ __align__(16) unsigned short Bs[128 * 64];
    char* AsB = (char*)As; char* BsB = (char*)Bs;
    int tid = threadIdx.x, lane = tid & 63, w = tid >> 6;
    int l15 = lane & 15, g = lane >> 4;
    int m0 = blockIdx.x * 128, n0 = blockIdx.y * 128;
    int wr = w >> 1, wc = w & 1;
    f32x4 acc[4][4] = {};

    for (int ks = 0; ks < 768; ks += 64) {
        __syncthreads();
#pragma unroll
        for (int i = 0; i < 4; i++) {
            int chunk = i * 256 + tid;
            int row = chunk >> 3, c8 = chunk & 7;
            gload16(AsB + chunk * 16, A + (size_t)(m0 + row) * 768 + ks + c8 * 8);
            gload16(BsB + chunk * 16, Bt + (size_t)(n0 + row) * 768 + ks + c8 * 8);
        }
        __syncthreads();
#pragma unroll
        for (int j = 0; j < 2; j++) {
            bf16x8 af[4], bf[4];
#pragma unroll
            for (int mb = 0; mb < 4; mb++) {
                int m = wr * 64 + mb * 16 + l15;
                af[mb] = *(const bf16x8*)(AsB + m * 128 + j * 64 + g * 16);
            }
#pragma unroll
            for (int nb = 0; nb < 4; nb++) {
                int n = wc * 64 + nb * 16 + l15;
                bf[nb] = *(const bf16x8*)(BsB + n * 128 + j * 64 + g * 16);
            }
#pragma unroll
            for (int mb = 0; mb < 4; mb++)
#pragma unroll
                for (int nb = 0; nb < 4; nb++)
                    acc[mb][nb] = mfma_bf16(af[mb], bf[nb], acc[mb][nb]);
        }
    }
#pragma unroll
    for (int nb = 0; nb < 4; nb++) {
        int n_g = n0 + wc * 64 + nb * 16 + l15;
        float bs = bias[n_g];
#pragma unroll
        for (int mb = 0; mb < 4; mb++) {
            f32x4 v = acc[mb][nb];
#pragma unroll
            for (int r = 0; r < 4; r++) {
                int m_g = m0 + wr * 64 + mb * 16 + g * 4 + r;
                out[(size_t)m_g * 768 + n_g] = v[r] + bs;
            }
        }
    }
}

// ---------------------------------------------------------------------------
extern "C" void kernel_launch(void* const* d_in, const int* in_sizes, int n_in,
                              void* d_out, int out_size, void* d_ws, size_t ws_size,
                              hipStream_t stream) {
    (void)in_sizes; (void)n_in; (void)out_size; (void)ws_size;
    const float* x      = (const float*)d_in[0];
    const int*   mask   = (const int*)d_in[1];
    const float* w_qkv  = (const float*)d_in[2];
    const float* b_qkv  = (const float*)d_in[3];
    const float* w_proj = (const float*)d_in[4];
    const float* b_proj = (const float*)d_in[5];
    const float* pb     = (const float*)d_in[6];
    (void)pb;

    float* out  = (float*)d_out;
    float* attO = out + (size_t)Bb * Nn * Cc;   // 6,291,456

    char* ws = (char*)d_ws;
    unsigned short* xb     = (unsigned short*)(ws);             // 12,582,912 B
    unsigned short* wqkvt  = (unsigned short*)(ws + 12582912);  //  3,538,944 B
    unsigned short* wprojt = (unsigned short*)(ws + 16121856);  //  1,179,648 B
    unsigned short* qbuf   = (unsigned short*)(ws + 17301504);  // 12,582,912 B
    unsigned short* kbuf   = (unsigned short*)(ws + 29884416);  // 12,582,912 B
    unsigned short* vtb    = (unsigned short*)(ws + 42467328);  // 12,582,912 B
    unsigned short* ctx    = (unsigned short*)(ws + 55050240);  // 12,582,912 B
    unsigned char*  mbits  = (unsigned char*)(ws + 67633152);   //      1,024 B

    k_cvt_bf16<<<6144, 256, 0, stream>>>(x, xb, 1572864);
    k_transpose_bf16<<<dim3(12, 36), 256, 0, stream>>>(w_qkv, wqkvt, 768, 2304);
    k_transpose_bf16<<<dim3(12, 12), 256, 0, stream>>>(w_proj, wprojt, 768, 768);
    k_maskbits<<<4, 256, 0, stream>>>(mask, mbits);
    k_gemm_qkv<<<dim3(64, 18), 256, 0, stream>>>(xb, wqkvt, b_qkv, qbuf, kbuf, vtb);
    k_attn<<<3072, 256, 0, stream>>>(qbuf, kbuf, vtb, (const unsigned*)mbits, attO, ctx);
    k_gemm_proj<<<dim3(64, 6), 256, 0, stream>>>(ctx, wprojt, b_proj, out);
}

// Round 12
// 405.627 us; speedup vs baseline: 1.1292x; 1.0372x over previous
//
#include <hip/hip_runtime.h>

// ---------------------------------------------------------------------------
// MultiHeadSelfAttention: x[4,2048,768] -> (out[4,2048,768], att[4,12,2048,2048])
// Pipeline: cvt/transpose -> QKV GEMM -> maskbits -> fused attention -> proj GEMM
// R12 = R11 with pipelined GEMMs: BK=32 double-buffered LDS (stage-before-
// compute, one barrier/step) + XOR-swizzled staging/reads (16-way -> 4-way
// bank conflict). k_attn byte-identical to R11.
// ---------------------------------------------------------------------------

typedef __attribute__((ext_vector_type(8)))  short          bf16x8;   // 8 bf16 (4 VGPR)
typedef __attribute__((ext_vector_type(4)))  float          f32x4;
typedef __attribute__((ext_vector_type(16))) float          f32x16;
typedef __attribute__((ext_vector_type(4)))  unsigned short us4;
typedef __attribute__((ext_vector_type(8)))  unsigned short us8;
typedef __attribute__((ext_vector_type(4)))  int            i32x4;
typedef __attribute__((ext_vector_type(4)))  unsigned int   u32x4;
typedef __attribute__((ext_vector_type(2)))  unsigned int   u32x2;

#define DEVFN static __device__ __forceinline__

enum : int { Bb = 4, Nn = 2048, Cc = 768, Hh = 12, Dd = 64, BH = 48, Mm = 8192, C3 = 2304 };

DEVFN unsigned short f2bf(float f) {
    unsigned int u = __float_as_uint(f);
    u = (u + 0x7fffu + ((u >> 16) & 1u)) >> 16;   // RNE
    return (unsigned short)u;
}

DEVFN void gload16(void* lds, const void* g) {
    __builtin_amdgcn_global_load_lds(
        (__attribute__((address_space(1))) void*)(g),
        (__attribute__((address_space(3))) void*)(lds), 16, 0, 0);
}

DEVFN f32x4 mfma_bf16(bf16x8 a, bf16x8 b, f32x4 c) {
    return __builtin_amdgcn_mfma_f32_16x16x32_bf16(a, b, c, 0, 0, 0);
}
DEVFN f32x16 mfma32(bf16x8 a, bf16x8 b, f32x16 c) {
    return __builtin_amdgcn_mfma_f32_32x32x16_bf16(a, b, c, 0, 0, 0);
}
DEVFN unsigned cvt_pk_bf16(float lo, float hi) {
    unsigned r;
    asm("v_cvt_pk_bf16_f32 %0, %1, %2" : "=v"(r) : "v"(lo), "v"(hi));
    return r;
}

// ---------------------------------------------------------------- cvt x->bf16
__global__ __launch_bounds__(256) void k_cvt_bf16(const float* __restrict__ in,
                                                  unsigned short* __restrict__ out, int n4) {
    int i = blockIdx.x * 256 + threadIdx.x;
    if (i < n4) {
        f32x4 v = ((const f32x4*)in)[i];
        us4 o;
        o[0] = f2bf(v[0]); o[1] = f2bf(v[1]); o[2] = f2bf(v[2]); o[3] = f2bf(v[3]);
        ((us4*)out)[i] = o;
    }
}

// ------------------------------------------------- transpose f32[R][C] -> bf16[C][R]
__global__ __launch_bounds__(256) void k_transpose_bf16(const float* __restrict__ in,
                                                        unsigned short* __restrict__ out,
                                                        int R, int Ccols) {
    __shared__ float t[64][65];
    int r0 = blockIdx.x * 64, c0 = blockIdx.y * 64;
    int tid = threadIdx.x;
#pragma unroll
    for (int i = 0; i < 16; i++) {
        int idx = i * 256 + tid; int lr = idx >> 6, lc = idx & 63;
        t[lr][lc] = in[(size_t)(r0 + lr) * Ccols + c0 + lc];
    }
    __syncthreads();
#pragma unroll
    for (int i = 0; i < 16; i++) {
        int idx = i * 256 + tid; int lc = idx >> 6, lr = idx & 63;
        out[(size_t)(c0 + lc) * R + r0 + lr] = f2bf(t[lr][lc]);
    }
}

// ------------------------------------------------- mask -> bitmask (4 x 64 u32)
__global__ __launch_bounds__(256) void k_maskbits(const int* __restrict__ mask,
                                                  unsigned char* __restrict__ mb) {
    int b = blockIdx.x, t = threadIdx.x;
    const int* mp = mask + b * 2048 + t * 8;
    unsigned byte = 0;
#pragma unroll
    for (int i = 0; i < 8; i++) byte |= (mp[i] ? 1u : 0u) << i;
    mb[b * 256 + t] = (unsigned char)byte;
}

// ------------------------------------------------------------- GEMM staging
// BK=32 tile stage: [128][32] bf16 = 8192B per matrix, XOR-swizzled source
// (c8 ^= row&3) so the ds_read side can un-swizzle (rule: both sides or neither).
#define GSTAGE(DSTA, DSTB, SRCA, SRCB, KS)                                     \
    {                                                                           \
        _Pragma("unroll")                                                       \
        for (int i_ = 0; i_ < 2; i_++) {                                        \
            int chunk_ = i_ * 256 + tid;                                        \
            int row_ = chunk_ >> 2, c8_ = (chunk_ & 3) ^ (row_ & 3);            \
            gload16((DSTA) + chunk_ * 16,                                       \
                    (SRCA) + (size_t)(m0 + row_) * 768 + (KS) + c8_ * 8);       \
            gload16((DSTB) + chunk_ * 16,                                       \
                    (SRCB) + (size_t)(n0 + row_) * 768 + (KS) + c8_ * 8);       \
        }                                                                       \
    }

#define GCOMPUTE(ABUF, BBUF)                                                    \
    {                                                                           \
        bf16x8 af[4], bf[4];                                                    \
        _Pragma("unroll")                                                       \
        for (int mb = 0; mb < 4; mb++) {                                        \
            int m_ = wr * 64 + mb * 16 + l15;                                   \
            af[mb] = *(const bf16x8*)((ABUF) + m_ * 64 + ((g ^ (m_ & 3)) << 4));\
        }                                                                       \
        _Pragma("unroll")                                                       \
        for (int nb = 0; nb < 4; nb++) {                                        \
            int n_ = wc * 64 + nb * 16 + l15;                                   \
            bf[nb] = *(const bf16x8*)((BBUF) + n_ * 64 + ((g ^ (n_ & 3)) << 4));\
        }                                                                       \
        _Pragma("unroll")                                                       \
        for (int mb = 0; mb < 4; mb++)                                          \
            _Pragma("unroll")                                                   \
            for (int nb = 0; nb < 4; nb++)                                      \
                acc[mb][nb] = mfma_bf16(af[mb], bf[nb], acc[mb][nb]);           \
    }

// ------------------------------------------------------------- QKV GEMM
__global__ __launch_bounds__(256) void k_gemm_qkv(const unsigned short* __restrict__ A,
                                                  const unsigned short* __restrict__ Bt,
                                                  const float* __restrict__ bias,
                                                  unsigned short* __restrict__ qO,
                                                  unsigned short* __restrict__ kO,
                                                  unsigned short* __restrict__ vT) {
    __shared__ __align__(16) char smem[51200];
    // A0 @0, B0 @8192, A1 @16384, B1 @24576, Ts @32768 (18432B)
    char* TsB = smem + 32768;
    int tid = threadIdx.x, lane = tid & 63, w = tid >> 6;
    int l15 = lane & 15, g = lane >> 4;
    int m0 = blockIdx.x * 128, n0 = blockIdx.y * 128;
    int wr = w >> 1, wc = w & 1;
    f32x4 acc[4][4] = {};

    GSTAGE(smem, smem + 8192, A, Bt, 0);
    __syncthreads();
    int cur = 0;
    for (int t = 0; t < 24; t++) {
        if (t < 23)
            GSTAGE(smem + (cur ^ 1) * 16384, smem + (cur ^ 1) * 16384 + 8192, A, Bt, (t + 1) * 32);
        GCOMPUTE(smem + cur * 16384, smem + cur * 16384 + 8192);
        __syncthreads();
        cur ^= 1;
    }

    int which = n0 / 768;                 // 0=q 1=k 2=v (uniform per block)
    float bscale = (which == 0) ? 0.125f : 1.0f;
    unsigned short* Ts = (unsigned short*)TsB;

    for (int mh = 0; mh < 2; mh++) {
        if (mh) __syncthreads();
        if (wr == mh) {
#pragma unroll
            for (int nb = 0; nb < 4; nb++) {
                int n_loc = wc * 64 + nb * 16 + l15;
                float bs = bias[n0 + n_loc];
#pragma unroll
                for (int mb = 0; mb < 4; mb++) {
                    f32x4 v = acc[mb][nb];
#pragma unroll
                    for (int r = 0; r < 4; r++) {
                        int m_loc = mb * 16 + g * 4 + r;
                        unsigned short bv = f2bf((v[r] + bs) * bscale);
                        if (which < 2)
                            Ts[m_loc * 136 + n_loc] = bv;
                        else
                            Ts[n_loc * 72 + m_loc] = bv;
                    }
                }
            }
        }
        __syncthreads();
        if (which < 2) {
            int row = tid >> 2, hh = (tid >> 1) & 1, qq = tid & 1;
            int m_g = m0 + mh * 64 + row;
            int bI = m_g >> 11, tok = m_g & 2047;
            int h = ((n0 + hh * 64) - which * 768) >> 6;
            unsigned short* dst = (which == 0 ? qO : kO)
                                  + (size_t)((bI * 12 + h) * 2048 + tok) * 64 + qq * 32;
            const unsigned short* src = Ts + row * 136 + hh * 64 + qq * 32;
#pragma unroll
            for (int j = 0; j < 4; j++)
                *(us8*)(dst + j * 8) = *(const us8*)(src + j * 8);
        } else {
            int drow = tid >> 1, seg = tid & 1;
            int n_g = n0 + drow;
            int h = (n_g - 1536) >> 6, d = n_g & 63;
            int bI = m0 >> 11;
            unsigned short* dst = vT + (size_t)((bI * 12 + h) * 64 + d) * 2048
                                  + (m0 & 2047) + mh * 64 + seg * 32;
            const unsigned short* src = Ts + drow * 72 + seg * 32;
#pragma unroll
            for (int j = 0; j < 4; j++)
                *(us8*)(dst + j * 8) = *(const us8*)(src + j * 8);
        }
    }
}

// ------------------------------------------------------------- fused attention
#define LOADKV(K0, Kf0, Kf1, Kf2, Kf3, Vf0, Vf1, Vf2, Vf3)            \
    {                                                                  \
        const unsigned short* kpt_ = kp + (size_t)(K0) * 64;           \
        Kf0 = *(const bf16x8*)(kpt_);                                  \
        Kf1 = *(const bf16x8*)(kpt_ + 16);                             \
        Kf2 = *(const bf16x8*)(kpt_ + 32);                             \
        Kf3 = *(const bf16x8*)(kpt_ + 48);                             \
        Vf0 = *(const bf16x8*)(vp + (K0));                             \
        Vf1 = *(const bf16x8*)(vp + (K0) + 16);                        \
        Vf2 = *(const bf16x8*)(vp + 65536 + (K0));                     \
        Vf3 = *(const bf16x8*)(vp + 65536 + (K0) + 16);                \
    }

#define BQUAD(J, S0, S1, S2, S3, MW, SROW, PKA, PKB)                                   \
    {                                                                                   \
        float e0 = __expf(fminf(S0, 75.f)) * rinv;                                      \
        float e1 = __expf(fminf(S1, 75.f)) * rinv;                                      \
        float e2 = __expf(fminf(S2, 75.f)) * rinv;                                      \
        float e3 = __expf(fminf(S3, 75.f)) * rinv;                                      \
        float a0 = ((MW >> (shv + 8 * (J) + 0)) & 1) ? e0 : 0.f;                        \
        float a1 = ((MW >> (shv + 8 * (J) + 1)) & 1) ? e1 : 0.f;                        \
        float a2 = ((MW >> (shv + 8 * (J) + 2)) & 1) ? e2 : 0.f;                        \
        float a3 = ((MW >> (shv + 8 * (J) + 3)) & 1) ? e3 : 0.f;                        \
        f32x4 av = {a0, a1, a2, a3};                                                    \
        *(f32x4*)((SROW) + 8 * (J)) = av;                                               \
        PKA = cvt_pk_bf16(a0, a1);                                                      \
        PKB = cvt_pk_bf16(a2, a3);                                                      \
    }

#define BTILE(Kf0, Kf1, Kf2, Kf3, Vf0, Vf1, Vf2, Vf3, MW, TT)                           \
    {                                                                                   \
        f32x16 s = {};                                                                  \
        s = mfma32(Kf0, qf0, s);                                                        \
        s = mfma32(Kf1, qf1, s);                                                        \
        s = mfma32(Kf2, qf2, s);                                                        \
        s = mfma32(Kf3, qf3, s);                                                        \
        float* srow = myS + l31 * 67 + (TT) * 32 + 4 * hi;                              \
        unsigned pk00, pk01, pk10, pk11, pk20, pk21, pk30, pk31;                        \
        BQUAD(0, s[0], s[1], s[2], s[3], MW, srow, pk00, pk01)                          \
        BQUAD(1, s[4], s[5], s[6], s[7], MW, srow, pk10, pk11)                          \
        BQUAD(2, s[8], s[9], s[10], s[11], MW, srow, pk20, pk21)                        \
        BQUAD(3, s[12], s[13], s[14], s[15], MW, srow, pk30, pk31)                      \
        {                                                                               \
            u32x2 sA = __builtin_amdgcn_permlane32_swap(pk00, pk10, false, false);      \
            u32x2 sB = __builtin_amdgcn_permlane32_swap(pk01, pk11, false, false);      \
            u32x4 bi = {sA[0], sB[0], sA[1], sB[1]};                                    \
            bf16x8 pf = __builtin_bit_cast(bf16x8, bi);                                 \
            c0 = mfma32(Vf0, pf, c0);                                                   \
            c1 = mfma32(Vf2, pf, c1);                                                   \
        }                                                                               \
        {                                                                               \
            u32x2 sA = __builtin_amdgcn_permlane32_swap(pk20, pk30, false, false);      \
            u32x2 sB = __builtin_amdgcn_permlane32_swap(pk21, pk31, false, false);      \
            u32x4 bi = {sA[0], sB[0], sA[1], sB[1]};                                    \
            bf16x8 pf = __builtin_bit_cast(bf16x8, bi);                                 \
            c0 = mfma32(Vf1, pf, c0);                                                   \
            c1 = mfma32(Vf3, pf, c1);                                                   \
        }                                                                               \
    }

// (byte-identical to R11)
__global__ __launch_bounds__(256, 3) void k_attn(const unsigned short* __restrict__ qb,
                                                 const unsigned short* __restrict__ kbuf,
                                                 const unsigned short* __restrict__ vT,
                                                 const unsigned* __restrict__ maskbits,
                                                 float* __restrict__ attO,
                                                 unsigned short* __restrict__ ctx) {
    __shared__ __align__(16) char smem[34304 + 512 + 128];
    float* Ssm    = (float*)smem;
    float* l_part = (float*)(smem + 34304);   // [4][32]
    float* rowinv = (float*)(smem + 34816);   // [32]

    int tid = threadIdx.x, lane = tid & 63, w = tid >> 6;   // w = 0..3
    int l31 = lane & 31, hi = lane >> 5;
    int n = blockIdx.x;
    int xcd = n & 7, slot = n >> 3;
    int bh = xcd * 6 + (slot >> 6), qt = slot & 63;
    int b = bh / 12, h = bh - b * 12;
    int q0 = qt * 32;
    int shv = 4 * hi;

    const unsigned short* kbase = kbuf + (size_t)bh * 2048 * 64;
    const unsigned short* vbase = vT + (size_t)bh * 64 * 2048;
    const unsigned* mwrds = maskbits + b * 64;

    bf16x8 qf0, qf1, qf2, qf3;
    {
        const unsigned short* qp = qb + (size_t)(bh * 2048 + q0 + l31) * 64 + hi * 8;
        qf0 = *(const bf16x8*)(qp);
        qf1 = *(const bf16x8*)(qp + 16);
        qf2 = *(const bf16x8*)(qp + 32);
        qf3 = *(const bf16x8*)(qp + 48);
    }
    const unsigned short* kp = kbase + (size_t)l31 * 64 + hi * 8;
    const unsigned short* vp = vbase + (size_t)l31 * 2048 + hi * 8;

    // ---------------- Phase A: lsum over wave's k-slice ----------------
    float lsum = 0.f;
#pragma unroll 2
    for (int t = 0; t < 16; t++) {
        int k0 = w * 512 + t * 32;
        const unsigned short* kpt = kp + (size_t)k0 * 64;
        bf16x8 kf0 = *(const bf16x8*)(kpt);
        bf16x8 kf1 = *(const bf16x8*)(kpt + 16);
        bf16x8 kf2 = *(const bf16x8*)(kpt + 32);
        bf16x8 kf3 = *(const bf16x8*)(kpt + 48);
        unsigned mw = mwrds[k0 >> 5];
        f32x16 s = {};
        s = mfma32(kf0, qf0, s);
        s = mfma32(kf1, qf1, s);
        s = mfma32(kf2, qf2, s);
        s = mfma32(kf3, qf3, s);
#pragma unroll
        for (int r = 0; r < 16; r++) {
            float e = __expf(fminf(s[r], 75.f));
            lsum += ((mw >> (shv + (r & 3) + 8 * (r >> 2))) & 1) ? e : 0.f;
        }
    }
    lsum += __shfl_xor(lsum, 32, 64);
    if (hi == 0) l_part[w * 32 + l31] = lsum;
    __syncthreads();
    if (tid < 32)
        rowinv[tid] = 1.0f / (l_part[tid] + l_part[32 + tid] + l_part[64 + tid] + l_part[96 + tid]);
    __syncthreads();
    float rinv = rowinv[l31];

    // ---------------- Phase B: pipelined, barrier-free ----------------
    float* myS = Ssm + w * 2144;               // [32][67] f32, private to wave w
    float* attW = attO + (size_t)(bh * 2048 + q0) * 2048 + w * 64;

    bf16x8 ka0, ka1, ka2, ka3, va0, va1, va2, va3;
    bf16x8 kb0, kb1, kb2, kb3, vb0, vb1, vb2, vb3;
    unsigned mwA, mwB;
    {
        int k0 = w * 64;
        LOADKV(k0, ka0, ka1, ka2, ka3, va0, va1, va2, va3);
        mwA = mwrds[k0 >> 5];
        LOADKV(k0 + 32, kb0, kb1, kb2, kb3, vb0, vb1, vb2, vb3);
        mwB = mwrds[(k0 + 32) >> 5];
    }

    f32x16 c0 = {}, c1 = {};
    for (int p = 0; p < 8; p++) {
        BTILE(ka0, ka1, ka2, ka3, va0, va1, va2, va3, mwA, 0);
        BTILE(kb0, kb1, kb2, kb3, vb0, vb1, vb2, vb3, mwB, 1);
        if (p < 7) {   // prefetch next phase BEFORE this phase's stores
            int nk = (p + 1) * 256 + w * 64;
            LOADKV(nk, ka0, ka1, ka2, ka3, va0, va1, va2, va3);
            mwA = mwrds[nk >> 5];
            LOADKV(nk + 32, kb0, kb1, kb2, kb3, vb0, vb1, vb2, vb3);
            mwB = mwrds[(nk + 32) >> 5];
        }
        asm volatile("" ::: "memory");   // pin: loads above, stores below
        {
            int rsub = lane >> 4, c16 = lane & 15;
#pragma unroll
            for (int st = 0; st < 8; st++) {
                int row = st * 4 + rsub;
                f32x4 v = *(const f32x4*)(myS + row * 67 + c16 * 4);
                __builtin_nontemporal_store(v,
                    (f32x4*)(attW + (size_t)row * 2048 + p * 256 + c16 * 4));
            }
        }
    }

    // ---------------- ctx: two-step wave-partial reduction ----------------
    __syncthreads();
    {
        float* cw = Ssm + w * 2080 + l31 * 65;   // [4][32][65] overlay
#pragma unroll
        for (int r = 0; r < 16; r++) {
            int d = (r & 3) + 8 * (r >> 2) + 4 * hi;
            cw[d] = c0[r];
            cw[d + 32] = c1[r];
        }
    }
    __syncthreads();
    {
        int q = tid >> 3, d0 = (tid & 7) * 8;
        float a[8];
#pragma unroll
        for (int j = 0; j < 8; j++) a[j] = 0.f;
#pragma unroll
        for (int w2 = 0; w2 < 4; w2++) {
            const float* cw = Ssm + w2 * 2080 + q * 65 + d0;
#pragma unroll
            for (int j = 0; j < 8; j++) a[j] += cw[j];
        }
        us4 o0, o1;
        o0[0] = f2bf(a[0]); o0[1] = f2bf(a[1]); o0[2] = f2bf(a[2]); o0[3] = f2bf(a[3]);
        o1[0] = f2bf(a[4]); o1[1] = f2bf(a[5]); o1[2] = f2bf(a[6]); o1[3] = f2bf(a[7]);
        unsigned short* cp = ctx + (size_t)(b * 2048 + q0 + q) * 768 + h * 64 + d0;
        *(us4*)(cp) = o0;
        *(us4*)(cp + 4) = o1;
    }
}

// ------------------------------------------------------------- proj GEMM
__global__ __launch_bounds__(256) void k_gemm_proj(const unsigned short* __restrict__ A,
                                                   const unsigned short* __restrict__ Bt,
                                                   const float* __restrict__ bias,
                                                   float* __restrict__ out) {
    __shared__ __align__(16) char smem[32768];
    int tid = threadIdx.x, lane = tid & 63, w = tid >> 6;
    int l15 = lane & 15, g = lane >> 4;
    int m0 = blockIdx.x * 128, n0 = blockIdx.y * 128;
    int wr = w >> 1, wc = w & 1;
    f32x4 acc[4][4] = {};

    GSTAGE(smem, smem + 8192, A, Bt, 0);
    __syncthreads();
    int cur = 0;
    for (int t = 0; t < 24; t++) {
        if (t < 23)
            GSTAGE(smem + (cur ^ 1) * 16384, smem + (cur ^ 1) * 16384 + 8192, A, Bt, (t + 1) * 32);
        GCOMPUTE(smem + cur * 16384, smem + cur * 16384 + 8192);
        __syncthreads();
        cur ^= 1;
    }
#pragma unroll
    for (int nb = 0; nb < 4; nb++) {
        int n_g = n0 + wc * 64 + nb * 16 + l15;
        float bs = bias[n_g];
#pragma unroll
        for (int mb = 0; mb < 4; mb++) {
            f32x4 v = acc[mb][nb];
#pragma unroll
            for (int r = 0; r < 4; r++) {
                int m_g = m0 + wr * 64 + mb * 16 + g * 4 + r;
                out[(size_t)m_g * 768 + n_g] = v[r] + bs;
            }
        }
    }
}

// ---------------------------------------------------------------------------
extern "C" void kernel_launch(void* const* d_in, const int* in_sizes, int n_in,
                              void* d_out, int out_size, void* d_ws, size_t ws_size,
                              hipStream_t stream) {
    (void)in_sizes; (void)n_in; (void)out_size; (void)ws_size;
    const float* x      = (const float*)d_in[0];
    const int*   mask   = (const int*)d_in[1];
    const float* w_qkv  = (const float*)d_in[2];
    const float* b_qkv  = (const float*)d_in[3];
    const float* w_proj = (const float*)d_in[4];
    const float* b_proj = (const float*)d_in[5];
    const float* pb     = (const float*)d_in[6];
    (void)pb;

    float* out  = (float*)d_out;
    float* attO = out + (size_t)Bb * Nn * Cc;   // 6,291,456

    char* ws = (char*)d_ws;
    unsigned short* xb     = (unsigned short*)(ws);             // 12,582,912 B
    unsigned short* wqkvt  = (unsigned short*)(ws + 12582912);  //  3,538,944 B
    unsigned short* wprojt = (unsigned short*)(ws + 16121856);  //  1,179,648 B
    unsigned short* qbuf   = (unsigned short*)(ws + 17301504);  // 12,582,912 B
    unsigned short* kbuf   = (unsigned short*)(ws + 29884416);  // 12,582,912 B
    unsigned short* vtb    = (unsigned short*)(ws + 42467328);  // 12,582,912 B
    unsigned short* ctx    = (unsigned short*)(ws + 55050240);  // 12,582,912 B
    unsigned char*  mbits  = (unsigned char*)(ws + 67633152);   //      1,024 B

    k_cvt_bf16<<<6144, 256, 0, stream>>>(x, xb, 1572864);
    k_transpose_bf16<<<dim3(12, 36), 256, 0, stream>>>(w_qkv, wqkvt, 768, 2304);
    k_transpose_bf16<<<dim3(12, 12), 256, 0, stream>>>(w_proj, wprojt, 768, 768);
    k_maskbits<<<4, 256, 0, stream>>>(mask, mbits);
    k_gemm_qkv<<<dim3(64, 18), 256, 0, stream>>>(xb, wqkvt, b_qkv, qbuf, kbuf, vtb);
    k_attn<<<3072, 256, 0, stream>>>(qbuf, kbuf, vtb, (const unsigned*)mbits, attO, ctx);
    k_gemm_proj<<<dim3(64, 6), 256, 0, stream>>>(ctx, wprojt, b_proj, out);
}

// Round 13
// 386.125 us; speedup vs baseline: 1.1863x; 1.0505x over previous
//
#include <hip/hip_runtime.h>

// ---------------------------------------------------------------------------
// MultiHeadSelfAttention: x[4,2048,768] -> (out[4,2048,768], att[4,12,2048,2048])
// Pipeline: cvt/transpose -> QKV GEMM -> maskbits -> fused attention -> proj GEMM
// R13 = R12 + Phase-A register double-buffer (prefetch K tile t+1 before
// computing tile t) + s_setprio(1) around MFMA clusters (T5).
// ---------------------------------------------------------------------------

typedef __attribute__((ext_vector_type(8)))  short          bf16x8;   // 8 bf16 (4 VGPR)
typedef __attribute__((ext_vector_type(4)))  float          f32x4;
typedef __attribute__((ext_vector_type(16))) float          f32x16;
typedef __attribute__((ext_vector_type(4)))  unsigned short us4;
typedef __attribute__((ext_vector_type(8)))  unsigned short us8;
typedef __attribute__((ext_vector_type(4)))  int            i32x4;
typedef __attribute__((ext_vector_type(4)))  unsigned int   u32x4;
typedef __attribute__((ext_vector_type(2)))  unsigned int   u32x2;

#define DEVFN static __device__ __forceinline__

enum : int { Bb = 4, Nn = 2048, Cc = 768, Hh = 12, Dd = 64, BH = 48, Mm = 8192, C3 = 2304 };

DEVFN unsigned short f2bf(float f) {
    unsigned int u = __float_as_uint(f);
    u = (u + 0x7fffu + ((u >> 16) & 1u)) >> 16;   // RNE
    return (unsigned short)u;
}

DEVFN void gload16(void* lds, const void* g) {
    __builtin_amdgcn_global_load_lds(
        (__attribute__((address_space(1))) void*)(g),
        (__attribute__((address_space(3))) void*)(lds), 16, 0, 0);
}

DEVFN f32x4 mfma_bf16(bf16x8 a, bf16x8 b, f32x4 c) {
    return __builtin_amdgcn_mfma_f32_16x16x32_bf16(a, b, c, 0, 0, 0);
}
DEVFN f32x16 mfma32(bf16x8 a, bf16x8 b, f32x16 c) {
    return __builtin_amdgcn_mfma_f32_32x32x16_bf16(a, b, c, 0, 0, 0);
}
DEVFN unsigned cvt_pk_bf16(float lo, float hi) {
    unsigned r;
    asm("v_cvt_pk_bf16_f32 %0, %1, %2" : "=v"(r) : "v"(lo), "v"(hi));
    return r;
}

// ---------------------------------------------------------------- cvt x->bf16
__global__ __launch_bounds__(256) void k_cvt_bf16(const float* __restrict__ in,
                                                  unsigned short* __restrict__ out, int n4) {
    int i = blockIdx.x * 256 + threadIdx.x;
    if (i < n4) {
        f32x4 v = ((const f32x4*)in)[i];
        us4 o;
        o[0] = f2bf(v[0]); o[1] = f2bf(v[1]); o[2] = f2bf(v[2]); o[3] = f2bf(v[3]);
        ((us4*)out)[i] = o;
    }
}

// ------------------------------------------------- transpose f32[R][C] -> bf16[C][R]
__global__ __launch_bounds__(256) void k_transpose_bf16(const float* __restrict__ in,
                                                        unsigned short* __restrict__ out,
                                                        int R, int Ccols) {
    __shared__ float t[64][65];
    int r0 = blockIdx.x * 64, c0 = blockIdx.y * 64;
    int tid = threadIdx.x;
#pragma unroll
    for (int i = 0; i < 16; i++) {
        int idx = i * 256 + tid; int lr = idx >> 6, lc = idx & 63;
        t[lr][lc] = in[(size_t)(r0 + lr) * Ccols + c0 + lc];
    }
    __syncthreads();
#pragma unroll
    for (int i = 0; i < 16; i++) {
        int idx = i * 256 + tid; int lc = idx >> 6, lr = idx & 63;
        out[(size_t)(c0 + lc) * R + r0 + lr] = f2bf(t[lr][lc]);
    }
}

// ------------------------------------------------- mask -> bitmask (4 x 64 u32)
__global__ __launch_bounds__(256) void k_maskbits(const int* __restrict__ mask,
                                                  unsigned char* __restrict__ mb) {
    int b = blockIdx.x, t = threadIdx.x;
    const int* mp = mask + b * 2048 + t * 8;
    unsigned byte = 0;
#pragma unroll
    for (int i = 0; i < 8; i++) byte |= (mp[i] ? 1u : 0u) << i;
    mb[b * 256 + t] = (unsigned char)byte;
}

// ------------------------------------------------------------- GEMM staging
#define GSTAGE(DSTA, DSTB, SRCA, SRCB, KS)                                     \
    {                                                                           \
        _Pragma("unroll")                                                       \
        for (int i_ = 0; i_ < 2; i_++) {                                        \
            int chunk_ = i_ * 256 + tid;                                        \
            int row_ = chunk_ >> 2, c8_ = (chunk_ & 3) ^ (row_ & 3);            \
            gload16((DSTA) + chunk_ * 16,                                       \
                    (SRCA) + (size_t)(m0 + row_) * 768 + (KS) + c8_ * 8);       \
            gload16((DSTB) + chunk_ * 16,                                       \
                    (SRCB) + (size_t)(n0 + row_) * 768 + (KS) + c8_ * 8);       \
        }                                                                       \
    }

#define GCOMPUTE(ABUF, BBUF)                                                    \
    {                                                                           \
        bf16x8 af[4], bf[4];                                                    \
        _Pragma("unroll")                                                       \
        for (int mb = 0; mb < 4; mb++) {                                        \
            int m_ = wr * 64 + mb * 16 + l15;                                   \
            af[mb] = *(const bf16x8*)((ABUF) + m_ * 64 + ((g ^ (m_ & 3)) << 4));\
        }                                                                       \
        _Pragma("unroll")                                                       \
        for (int nb = 0; nb < 4; nb++) {                                        \
            int n_ = wc * 64 + nb * 16 + l15;                                   \
            bf[nb] = *(const bf16x8*)((BBUF) + n_ * 64 + ((g ^ (n_ & 3)) << 4));\
        }                                                                       \
        __builtin_amdgcn_s_setprio(1);                                          \
        _Pragma("unroll")                                                       \
        for (int mb = 0; mb < 4; mb++)                                          \
            _Pragma("unroll")                                                   \
            for (int nb = 0; nb < 4; nb++)                                      \
                acc[mb][nb] = mfma_bf16(af[mb], bf[nb], acc[mb][nb]);           \
        __builtin_amdgcn_s_setprio(0);                                          \
    }

// ------------------------------------------------------------- QKV GEMM
__global__ __launch_bounds__(256) void k_gemm_qkv(const unsigned short* __restrict__ A,
                                                  const unsigned short* __restrict__ Bt,
                                                  const float* __restrict__ bias,
                                                  unsigned short* __restrict__ qO,
                                                  unsigned short* __restrict__ kO,
                                                  unsigned short* __restrict__ vT) {
    __shared__ __align__(16) char smem[51200];
    char* TsB = smem + 32768;
    int tid = threadIdx.x, lane = tid & 63, w = tid >> 6;
    int l15 = lane & 15, g = lane >> 4;
    int m0 = blockIdx.x * 128, n0 = blockIdx.y * 128;
    int wr = w >> 1, wc = w & 1;
    f32x4 acc[4][4] = {};

    GSTAGE(smem, smem + 8192, A, Bt, 0);
    __syncthreads();
    int cur = 0;
    for (int t = 0; t < 24; t++) {
        if (t < 23)
            GSTAGE(smem + (cur ^ 1) * 16384, smem + (cur ^ 1) * 16384 + 8192, A, Bt, (t + 1) * 32);
        GCOMPUTE(smem + cur * 16384, smem + cur * 16384 + 8192);
        __syncthreads();
        cur ^= 1;
    }

    int which = n0 / 768;                 // 0=q 1=k 2=v (uniform per block)
    float bscale = (which == 0) ? 0.125f : 1.0f;
    unsigned short* Ts = (unsigned short*)TsB;

    for (int mh = 0; mh < 2; mh++) {
        if (mh) __syncthreads();
        if (wr == mh) {
#pragma unroll
            for (int nb = 0; nb < 4; nb++) {
                int n_loc = wc * 64 + nb * 16 + l15;
                float bs = bias[n0 + n_loc];
#pragma unroll
                for (int mb = 0; mb < 4; mb++) {
                    f32x4 v = acc[mb][nb];
#pragma unroll
                    for (int r = 0; r < 4; r++) {
                        int m_loc = mb * 16 + g * 4 + r;
                        unsigned short bv = f2bf((v[r] + bs) * bscale);
                        if (which < 2)
                            Ts[m_loc * 136 + n_loc] = bv;
                        else
                            Ts[n_loc * 72 + m_loc] = bv;
                    }
                }
            }
        }
        __syncthreads();
        if (which < 2) {
            int row = tid >> 2, hh = (tid >> 1) & 1, qq = tid & 1;
            int m_g = m0 + mh * 64 + row;
            int bI = m_g >> 11, tok = m_g & 2047;
            int h = ((n0 + hh * 64) - which * 768) >> 6;
            unsigned short* dst = (which == 0 ? qO : kO)
                                  + (size_t)((bI * 12 + h) * 2048 + tok) * 64 + qq * 32;
            const unsigned short* src = Ts + row * 136 + hh * 64 + qq * 32;
#pragma unroll
            for (int j = 0; j < 4; j++)
                *(us8*)(dst + j * 8) = *(const us8*)(src + j * 8);
        } else {
            int drow = tid >> 1, seg = tid & 1;
            int n_g = n0 + drow;
            int h = (n_g - 1536) >> 6, d = n_g & 63;
            int bI = m0 >> 11;
            unsigned short* dst = vT + (size_t)((bI * 12 + h) * 64 + d) * 2048
                                  + (m0 & 2047) + mh * 64 + seg * 32;
            const unsigned short* src = Ts + drow * 72 + seg * 32;
#pragma unroll
            for (int j = 0; j < 4; j++)
                *(us8*)(dst + j * 8) = *(const us8*)(src + j * 8);
        }
    }
}

// ------------------------------------------------------------- fused attention
#define LOADKV(K0, Kf0, Kf1, Kf2, Kf3, Vf0, Vf1, Vf2, Vf3)            \
    {                                                                  \
        const unsigned short* kpt_ = kp + (size_t)(K0) * 64;           \
        Kf0 = *(const bf16x8*)(kpt_);                                  \
        Kf1 = *(const bf16x8*)(kpt_ + 16);                             \
        Kf2 = *(const bf16x8*)(kpt_ + 32);                             \
        Kf3 = *(const bf16x8*)(kpt_ + 48);                             \
        Vf0 = *(const bf16x8*)(vp + (K0));                             \
        Vf1 = *(const bf16x8*)(vp + (K0) + 16);                        \
        Vf2 = *(const bf16x8*)(vp + 65536 + (K0));                     \
        Vf3 = *(const bf16x8*)(vp + 65536 + (K0) + 16);                \
    }

#define BQUAD(J, S0, S1, S2, S3, MW, SROW, PKA, PKB)                                   \
    {                                                                                   \
        float e0 = __expf(fminf(S0, 75.f)) * rinv;                                      \
        float e1 = __expf(fminf(S1, 75.f)) * rinv;                                      \
        float e2 = __expf(fminf(S2, 75.f)) * rinv;                                      \
        float e3 = __expf(fminf(S3, 75.f)) * rinv;                                      \
        float a0 = ((MW >> (shv + 8 * (J) + 0)) & 1) ? e0 : 0.f;                        \
        float a1 = ((MW >> (shv + 8 * (J) + 1)) & 1) ? e1 : 0.f;                        \
        float a2 = ((MW >> (shv + 8 * (J) + 2)) & 1) ? e2 : 0.f;                        \
        float a3 = ((MW >> (shv + 8 * (J) + 3)) & 1) ? e3 : 0.f;                        \
        f32x4 av = {a0, a1, a2, a3};                                                    \
        *(f32x4*)((SROW) + 8 * (J)) = av;                                               \
        PKA = cvt_pk_bf16(a0, a1);                                                      \
        PKB = cvt_pk_bf16(a2, a3);                                                      \
    }

#define BTILE(Kf0, Kf1, Kf2, Kf3, Vf0, Vf1, Vf2, Vf3, MW, TT)                           \
    {                                                                                   \
        f32x16 s = {};                                                                  \
        __builtin_amdgcn_s_setprio(1);                                                  \
        s = mfma32(Kf0, qf0, s);                                                        \
        s = mfma32(Kf1, qf1, s);                                                        \
        s = mfma32(Kf2, qf2, s);                                                        \
        s = mfma32(Kf3, qf3, s);                                                        \
        __builtin_amdgcn_s_setprio(0);                                                  \
        float* srow = myS + l31 * 67 + (TT) * 32 + 4 * hi;                              \
        unsigned pk00, pk01, pk10, pk11, pk20, pk21, pk30, pk31;                        \
        BQUAD(0, s[0], s[1], s[2], s[3], MW, srow, pk00, pk01)                          \
        BQUAD(1, s[4], s[5], s[6], s[7], MW, srow, pk10, pk11)                          \
        BQUAD(2, s[8], s[9], s[10], s[11], MW, srow, pk20, pk21)                        \
        BQUAD(3, s[12], s[13], s[14], s[15], MW, srow, pk30, pk31)                      \
        __builtin_amdgcn_s_setprio(1);                                                  \
        {                                                                               \
            u32x2 sA = __builtin_amdgcn_permlane32_swap(pk00, pk10, false, false);      \
            u32x2 sB = __builtin_amdgcn_permlane32_swap(pk01, pk11, false, false);      \
            u32x4 bi = {sA[0], sB[0], sA[1], sB[1]};                                    \
            bf16x8 pf = __builtin_bit_cast(bf16x8, bi);                                 \
            c0 = mfma32(Vf0, pf, c0);                                                   \
            c1 = mfma32(Vf2, pf, c1);                                                   \
        }                                                                               \
        {                                                                               \
            u32x2 sA = __builtin_amdgcn_permlane32_swap(pk20, pk30, false, false);      \
            u32x2 sB = __builtin_amdgcn_permlane32_swap(pk21, pk31, false, false);      \
            u32x4 bi = {sA[0], sB[0], sA[1], sB[1]};                                    \
            bf16x8 pf = __builtin_bit_cast(bf16x8, bi);                                 \
            c0 = mfma32(Vf1, pf, c0);                                                   \
            c1 = mfma32(Vf3, pf, c1);                                                   \
        }                                                                               \
        __builtin_amdgcn_s_setprio(0);                                                  \
    }

// 3072 WGs (48 bh x 64 q-tiles, XCD-bijective) x 256 threads (4 waves).
// Phase A: reg-double-buffered K prefetch (no stores -> no FIFO hazard), then
// one LDS reduce. Phase B: per-wave private LDS staging (no barriers), K/V
// register double-buffered with next-phase loads issued BEFORE the NT store
// burst (vmcnt FIFO). setprio(1) around MFMA clusters (T5).
__global__ __launch_bounds__(256, 3) void k_attn(const unsigned short* __restrict__ qb,
                                                 const unsigned short* __restrict__ kbuf,
                                                 const unsigned short* __restrict__ vT,
                                                 const unsigned* __restrict__ maskbits,
                                                 float* __restrict__ attO,
                                                 unsigned short* __restrict__ ctx) {
    __shared__ __align__(16) char smem[34304 + 512 + 128];
    float* Ssm    = (float*)smem;
    float* l_part = (float*)(smem + 34304);   // [4][32]
    float* rowinv = (float*)(smem + 34816);   // [32]

    int tid = threadIdx.x, lane = tid & 63, w = tid >> 6;   // w = 0..3
    int l31 = lane & 31, hi = lane >> 5;
    int n = blockIdx.x;
    int xcd = n & 7, slot = n >> 3;
    int bh = xcd * 6 + (slot >> 6), qt = slot & 63;
    int b = bh / 12, h = bh - b * 12;
    int q0 = qt * 32;
    int shv = 4 * hi;

    const unsigned short* kbase = kbuf + (size_t)bh * 2048 * 64;
    const unsigned short* vbase = vT + (size_t)bh * 64 * 2048;
    const unsigned* mwrds = maskbits + b * 64;

    bf16x8 qf0, qf1, qf2, qf3;
    {
        const unsigned short* qp = qb + (size_t)(bh * 2048 + q0 + l31) * 64 + hi * 8;
        qf0 = *(const bf16x8*)(qp);
        qf1 = *(const bf16x8*)(qp + 16);
        qf2 = *(const bf16x8*)(qp + 32);
        qf3 = *(const bf16x8*)(qp + 48);
    }
    const unsigned short* kp = kbase + (size_t)l31 * 64 + hi * 8;
    const unsigned short* vp = vbase + (size_t)l31 * 2048 + hi * 8;

    // ---------------- Phase A: lsum, reg-double-buffered ----------------
    float lsum = 0.f;
    {
        bf16x8 xa0, xa1, xa2, xa3, xb0, xb1, xb2, xb3;
        unsigned ma, mb2;
        int ks0 = w * 512;
        {
            const unsigned short* kpt = kp + (size_t)ks0 * 64;
            xa0 = *(const bf16x8*)(kpt);
            xa1 = *(const bf16x8*)(kpt + 16);
            xa2 = *(const bf16x8*)(kpt + 32);
            xa3 = *(const bf16x8*)(kpt + 48);
            ma = mwrds[ks0 >> 5];
        }
#pragma unroll 2
        for (int t = 0; t < 16; t++) {
            if (t < 15) {
                int nk = ks0 + (t + 1) * 32;
                const unsigned short* kpt = kp + (size_t)nk * 64;
                xb0 = *(const bf16x8*)(kpt);
                xb1 = *(const bf16x8*)(kpt + 16);
                xb2 = *(const bf16x8*)(kpt + 32);
                xb3 = *(const bf16x8*)(kpt + 48);
                mb2 = mwrds[nk >> 5];
            }
            f32x16 s = {};
            __builtin_amdgcn_s_setprio(1);
            s = mfma32(xa0, qf0, s);
            s = mfma32(xa1, qf1, s);
            s = mfma32(xa2, qf2, s);
            s = mfma32(xa3, qf3, s);
            __builtin_amdgcn_s_setprio(0);
#pragma unroll
            for (int r = 0; r < 16; r++) {
                float e = __expf(fminf(s[r], 75.f));
                lsum += ((ma >> (shv + (r & 3) + 8 * (r >> 2))) & 1) ? e : 0.f;
            }
            xa0 = xb0; xa1 = xb1; xa2 = xb2; xa3 = xb3; ma = mb2;
        }
    }
    lsum += __shfl_xor(lsum, 32, 64);
    if (hi == 0) l_part[w * 32 + l31] = lsum;
    __syncthreads();
    if (tid < 32)
        rowinv[tid] = 1.0f / (l_part[tid] + l_part[32 + tid] + l_part[64 + tid] + l_part[96 + tid]);
    __syncthreads();
    float rinv = rowinv[l31];

    // ---------------- Phase B: pipelined, barrier-free ----------------
    float* myS = Ssm + w * 2144;               // [32][67] f32, private to wave w
    float* attW = attO + (size_t)(bh * 2048 + q0) * 2048 + w * 64;

    bf16x8 ka0, ka1, ka2, ka3, va0, va1, va2, va3;
    bf16x8 kb0, kb1, kb2, kb3, vb0, vb1, vb2, vb3;
    unsigned mwA, mwB;
    {
        int k0 = w * 64;
        LOADKV(k0, ka0, ka1, ka2, ka3, va0, va1, va2, va3);
        mwA = mwrds[k0 >> 5];
        LOADKV(k0 + 32, kb0, kb1, kb2, kb3, vb0, vb1, vb2, vb3);
        mwB = mwrds[(k0 + 32) >> 5];
    }

    f32x16 c0 = {}, c1 = {};
    for (int p = 0; p < 8; p++) {
        BTILE(ka0, ka1, ka2, ka3, va0, va1, va2, va3, mwA, 0);
        BTILE(kb0, kb1, kb2, kb3, vb0, vb1, vb2, vb3, mwB, 1);
        if (p < 7) {   // prefetch next phase BEFORE this phase's stores
            int nk = (p + 1) * 256 + w * 64;
            LOADKV(nk, ka0, ka1, ka2, ka3, va0, va1, va2, va3);
            mwA = mwrds[nk >> 5];
            LOADKV(nk + 32, kb0, kb1, kb2, kb3, vb0, vb1, vb2, vb3);
            mwB = mwrds[(nk + 32) >> 5];
        }
        asm volatile("" ::: "memory");   // pin: loads above, stores below
        {
            int rsub = lane >> 4, c16 = lane & 15;
#pragma unroll
            for (int st = 0; st < 8; st++) {
                int row = st * 4 + rsub;
                f32x4 v = *(const f32x4*)(myS + row * 67 + c16 * 4);
                __builtin_nontemporal_store(v,
                    (f32x4*)(attW + (size_t)row * 2048 + p * 256 + c16 * 4));
            }
        }
    }

    // ---------------- ctx: two-step wave-partial reduction ----------------
    __syncthreads();
    {
        float* cw = Ssm + w * 2080 + l31 * 65;   // [4][32][65] overlay
#pragma unroll
        for (int r = 0; r < 16; r++) {
            int d = (r & 3) + 8 * (r >> 2) + 4 * hi;
            cw[d] = c0[r];
            cw[d + 32] = c1[r];
        }
    }
    __syncthreads();
    {
        int q = tid >> 3, d0 = (tid & 7) * 8;
        float a[8];
#pragma unroll
        for (int j = 0; j < 8; j++) a[j] = 0.f;
#pragma unroll
        for (int w2 = 0; w2 < 4; w2++) {
            const float* cw = Ssm + w2 * 2080 + q * 65 + d0;
#pragma unroll
            for (int j = 0; j < 8; j++) a[j] += cw[j];
        }
        us4 o0, o1;
        o0[0] = f2bf(a[0]); o0[1] = f2bf(a[1]); o0[2] = f2bf(a[2]); o0[3] = f2bf(a[3]);
        o1[0] = f2bf(a[4]); o1[1] = f2bf(a[5]); o1[2] = f2bf(a[6]); o1[3] = f2bf(a[7]);
        unsigned short* cp = ctx + (size_t)(b * 2048 + q0 + q) * 768 + h * 64 + d0;
        *(us4*)(cp) = o0;
        *(us4*)(cp + 4) = o1;
    }
}

// ------------------------------------------------------------- proj GEMM
__global__ __launch_bounds__(256) void k_gemm_proj(const unsigned short* __restrict__ A,
                                                   const unsigned short* __restrict__ Bt,
                                                   const float* __restrict__ bias,
                                                   float* __restrict__ out) {
    __shared__ __align__(16) char smem[32768];
    int tid = threadIdx.x, lane = tid & 63, w = tid >> 6;
    int l15 = lane & 15, g = lane >> 4;
    int m0 = blockIdx.x * 128, n0 = blockIdx.y * 128;
    int wr = w >> 1, wc = w & 1;
    f32x4 acc[4][4] = {};

    GSTAGE(smem, smem + 8192, A, Bt, 0);
    __syncthreads();
    int cur = 0;
    for (int t = 0; t < 24; t++) {
        if (t < 23)
            GSTAGE(smem + (cur ^ 1) * 16384, smem + (cur ^ 1) * 16384 + 8192, A, Bt, (t + 1) * 32);
        GCOMPUTE(smem + cur * 16384, smem + cur * 16384 + 8192);
        __syncthreads();
        cur ^= 1;
    }
#pragma unroll
    for (int nb = 0; nb < 4; nb++) {
        int n_g = n0 + wc * 64 + nb * 16 + l15;
        float bs = bias[n_g];
#pragma unroll
        for (int mb = 0; mb < 4; mb++) {
            f32x4 v = acc[mb][nb];
#pragma unroll
            for (int r = 0; r < 4; r++) {
                int m_g = m0 + wr * 64 + mb * 16 + g * 4 + r;
                out[(size_t)m_g * 768 + n_g] = v[r] + bs;
            }
        }
    }
}

// ---------------------------------------------------------------------------
extern "C" void kernel_launch(void* const* d_in, const int* in_sizes, int n_in,
                              void* d_out, int out_size, void* d_ws, size_t ws_size,
                              hipStream_t stream) {
    (void)in_sizes; (void)n_in; (void)out_size; (void)ws_size;
    const float* x      = (const float*)d_in[0];
    const int*   mask   = (const int*)d_in[1];
    const float* w_qkv  = (const float*)d_in[2];
    const float* b_qkv  = (const float*)d_in[3];
    const float* w_proj = (const float*)d_in[4];
    const float* b_proj = (const float*)d_in[5];
    const float* pb     = (const float*)d_in[6];
    (void)pb;

    float* out  = (float*)d_out;
    float* attO = out + (size_t)Bb * Nn * Cc;   // 6,291,456

    char* ws = (char*)d_ws;
    unsigned short* xb     = (unsigned short*)(ws);             // 12,582,912 B
    unsigned short* wqkvt  = (unsigned short*)(ws + 12582912);  //  3,538,944 B
    unsigned short* wprojt = (unsigned short*)(ws + 16121856);  //  1,179,648 B
    unsigned short* qbuf   = (unsigned short*)(ws + 17301504);  // 12,582,912 B
    unsigned short* kbuf   = (unsigned short*)(ws + 29884416);  // 12,582,912 B
    unsigned short* vtb    = (unsigned short*)(ws + 42467328);  // 12,582,912 B
    unsigned short* ctx    = (unsigned short*)(ws + 55050240);  // 12,582,912 B
    unsigned char*  mbits  = (unsigned char*)(ws + 67633152);   //      1,024 B

    k_cvt_bf16<<<6144, 256, 0, stream>>>(x, xb, 1572864);
    k_transpose_bf16<<<dim3(12, 36), 256, 0, stream>>>(w_qkv, wqkvt, 768, 2304);
    k_transpose_bf16<<<dim3(12, 12), 256, 0, stream>>>(w_proj, wprojt, 768, 768);
    k_maskbits<<<4, 256, 0, stream>>>(mask, mbits);
    k_gemm_qkv<<<dim3(64, 18), 256, 0, stream>>>(xb, wqkvt, b_qkv, qbuf, kbuf, vtb);
    k_attn<<<3072, 256, 0, stream>>>(qbuf, kbuf, vtb, (const unsigned*)mbits, attO, ctx);
    k_gemm_proj<<<dim3(64, 6), 256, 0, stream>>>(ctx, wprojt, b_proj, out);
}

// Round 14
// 383.479 us; speedup vs baseline: 1.1945x; 1.0069x over previous
//
#include <hip/hip_runtime.h>

// ---------------------------------------------------------------------------
// MultiHeadSelfAttention: x[4,2048,768] -> (out[4,2048,768], att[4,12,2048,2048])
// Pipeline: cvt/transpose -> QKV GEMM -> maskbits -> fused attention -> proj GEMM
// R14 = R13 + (a) 4-way-split lsum partials (breaks 256-deep serial FADD chain)
//            + (b) exp2 via log2e folded into Q scale (v_exp_f32 is 2^x natively)
// ---------------------------------------------------------------------------

typedef __attribute__((ext_vector_type(8)))  short          bf16x8;   // 8 bf16 (4 VGPR)
typedef __attribute__((ext_vector_type(4)))  float          f32x4;
typedef __attribute__((ext_vector_type(16))) float          f32x16;
typedef __attribute__((ext_vector_type(4)))  unsigned short us4;
typedef __attribute__((ext_vector_type(8)))  unsigned short us8;
typedef __attribute__((ext_vector_type(4)))  int            i32x4;
typedef __attribute__((ext_vector_type(4)))  unsigned int   u32x4;
typedef __attribute__((ext_vector_type(2)))  unsigned int   u32x2;

#define DEVFN static __device__ __forceinline__

enum : int { Bb = 4, Nn = 2048, Cc = 768, Hh = 12, Dd = 64, BH = 48, Mm = 8192, C3 = 2304 };

DEVFN unsigned short f2bf(float f) {
    unsigned int u = __float_as_uint(f);
    u = (u + 0x7fffu + ((u >> 16) & 1u)) >> 16;   // RNE
    return (unsigned short)u;
}

DEVFN void gload16(void* lds, const void* g) {
    __builtin_amdgcn_global_load_lds(
        (__attribute__((address_space(1))) void*)(g),
        (__attribute__((address_space(3))) void*)(lds), 16, 0, 0);
}

DEVFN f32x4 mfma_bf16(bf16x8 a, bf16x8 b, f32x4 c) {
    return __builtin_amdgcn_mfma_f32_16x16x32_bf16(a, b, c, 0, 0, 0);
}
DEVFN f32x16 mfma32(bf16x8 a, bf16x8 b, f32x16 c) {
    return __builtin_amdgcn_mfma_f32_32x32x16_bf16(a, b, c, 0, 0, 0);
}
DEVFN unsigned cvt_pk_bf16(float lo, float hi) {
    unsigned r;
    asm("v_cvt_pk_bf16_f32 %0, %1, %2" : "=v"(r) : "v"(lo), "v"(hi));
    return r;
}
DEVFN float fexp2(float x) { return __builtin_amdgcn_exp2f(x); }  // v_exp_f32 = 2^x

// ---------------------------------------------------------------- cvt x->bf16
__global__ __launch_bounds__(256) void k_cvt_bf16(const float* __restrict__ in,
                                                  unsigned short* __restrict__ out, int n4) {
    int i = blockIdx.x * 256 + threadIdx.x;
    if (i < n4) {
        f32x4 v = ((const f32x4*)in)[i];
        us4 o;
        o[0] = f2bf(v[0]); o[1] = f2bf(v[1]); o[2] = f2bf(v[2]); o[3] = f2bf(v[3]);
        ((us4*)out)[i] = o;
    }
}

// ------------------------------------------------- transpose f32[R][C] -> bf16[C][R]
__global__ __launch_bounds__(256) void k_transpose_bf16(const float* __restrict__ in,
                                                        unsigned short* __restrict__ out,
                                                        int R, int Ccols) {
    __shared__ float t[64][65];
    int r0 = blockIdx.x * 64, c0 = blockIdx.y * 64;
    int tid = threadIdx.x;
#pragma unroll
    for (int i = 0; i < 16; i++) {
        int idx = i * 256 + tid; int lr = idx >> 6, lc = idx & 63;
        t[lr][lc] = in[(size_t)(r0 + lr) * Ccols + c0 + lc];
    }
    __syncthreads();
#pragma unroll
    for (int i = 0; i < 16; i++) {
        int idx = i * 256 + tid; int lc = idx >> 6, lr = idx & 63;
        out[(size_t)(c0 + lc) * R + r0 + lr] = f2bf(t[lr][lc]);
    }
}

// ------------------------------------------------- mask -> bitmask (4 x 64 u32)
__global__ __launch_bounds__(256) void k_maskbits(const int* __restrict__ mask,
                                                  unsigned char* __restrict__ mb) {
    int b = blockIdx.x, t = threadIdx.x;
    const int* mp = mask + b * 2048 + t * 8;
    unsigned byte = 0;
#pragma unroll
    for (int i = 0; i < 8; i++) byte |= (mp[i] ? 1u : 0u) << i;
    mb[b * 256 + t] = (unsigned char)byte;
}

// ------------------------------------------------------------- GEMM staging
#define GSTAGE(DSTA, DSTB, SRCA, SRCB, KS)                                     \
    {                                                                           \
        _Pragma("unroll")                                                       \
        for (int i_ = 0; i_ < 2; i_++) {                                        \
            int chunk_ = i_ * 256 + tid;                                        \
            int row_ = chunk_ >> 2, c8_ = (chunk_ & 3) ^ (row_ & 3);            \
            gload16((DSTA) + chunk_ * 16,                                       \
                    (SRCA) + (size_t)(m0 + row_) * 768 + (KS) + c8_ * 8);       \
            gload16((DSTB) + chunk_ * 16,                                       \
                    (SRCB) + (size_t)(n0 + row_) * 768 + (KS) + c8_ * 8);       \
        }                                                                       \
    }

#define GCOMPUTE(ABUF, BBUF)                                                    \
    {                                                                           \
        bf16x8 af[4], bf[4];                                                    \
        _Pragma("unroll")                                                       \
        for (int mb = 0; mb < 4; mb++) {                                        \
            int m_ = wr * 64 + mb * 16 + l15;                                   \
            af[mb] = *(const bf16x8*)((ABUF) + m_ * 64 + ((g ^ (m_ & 3)) << 4));\
        }                                                                       \
        _Pragma("unroll")                                                       \
        for (int nb = 0; nb < 4; nb++) {                                        \
            int n_ = wc * 64 + nb * 16 + l15;                                   \
            bf[nb] = *(const bf16x8*)((BBUF) + n_ * 64 + ((g ^ (n_ & 3)) << 4));\
        }                                                                       \
        __builtin_amdgcn_s_setprio(1);                                          \
        _Pragma("unroll")                                                       \
        for (int mb = 0; mb < 4; mb++)                                          \
            _Pragma("unroll")                                                   \
            for (int nb = 0; nb < 4; nb++)                                      \
                acc[mb][nb] = mfma_bf16(af[mb], bf[nb], acc[mb][nb]);           \
        __builtin_amdgcn_s_setprio(0);                                          \
    }

// ------------------------------------------------------------- QKV GEMM
__global__ __launch_bounds__(256) void k_gemm_qkv(const unsigned short* __restrict__ A,
                                                  const unsigned short* __restrict__ Bt,
                                                  const float* __restrict__ bias,
                                                  unsigned short* __restrict__ qO,
                                                  unsigned short* __restrict__ kO,
                                                  unsigned short* __restrict__ vT) {
    __shared__ __align__(16) char smem[51200];
    char* TsB = smem + 32768;
    int tid = threadIdx.x, lane = tid & 63, w = tid >> 6;
    int l15 = lane & 15, g = lane >> 4;
    int m0 = blockIdx.x * 128, n0 = blockIdx.y * 128;
    int wr = w >> 1, wc = w & 1;
    f32x4 acc[4][4] = {};

    GSTAGE(smem, smem + 8192, A, Bt, 0);
    __syncthreads();
    int cur = 0;
    for (int t = 0; t < 24; t++) {
        if (t < 23)
            GSTAGE(smem + (cur ^ 1) * 16384, smem + (cur ^ 1) * 16384 + 8192, A, Bt, (t + 1) * 32);
        GCOMPUTE(smem + cur * 16384, smem + cur * 16384 + 8192);
        __syncthreads();
        cur ^= 1;
    }

    int which = n0 / 768;                 // 0=q 1=k 2=v (uniform per block)
    // q scale folds D^-0.5 AND log2(e) so attn can use v_exp_f32 (2^x) directly
    float bscale = (which == 0) ? 0.125f * 1.4426950408889634f : 1.0f;
    unsigned short* Ts = (unsigned short*)TsB;

    for (int mh = 0; mh < 2; mh++) {
        if (mh) __syncthreads();
        if (wr == mh) {
#pragma unroll
            for (int nb = 0; nb < 4; nb++) {
                int n_loc = wc * 64 + nb * 16 + l15;
                float bs = bias[n0 + n_loc];
#pragma unroll
                for (int mb = 0; mb < 4; mb++) {
                    f32x4 v = acc[mb][nb];
#pragma unroll
                    for (int r = 0; r < 4; r++) {
                        int m_loc = mb * 16 + g * 4 + r;
                        unsigned short bv = f2bf((v[r] + bs) * bscale);
                        if (which < 2)
                            Ts[m_loc * 136 + n_loc] = bv;
                        else
                            Ts[n_loc * 72 + m_loc] = bv;
                    }
                }
            }
        }
        __syncthreads();
        if (which < 2) {
            int row = tid >> 2, hh = (tid >> 1) & 1, qq = tid & 1;
            int m_g = m0 + mh * 64 + row;
            int bI = m_g >> 11, tok = m_g & 2047;
            int h = ((n0 + hh * 64) - which * 768) >> 6;
            unsigned short* dst = (which == 0 ? qO : kO)
                                  + (size_t)((bI * 12 + h) * 2048 + tok) * 64 + qq * 32;
            const unsigned short* src = Ts + row * 136 + hh * 64 + qq * 32;
#pragma unroll
            for (int j = 0; j < 4; j++)
                *(us8*)(dst + j * 8) = *(const us8*)(src + j * 8);
        } else {
            int drow = tid >> 1, seg = tid & 1;
            int n_g = n0 + drow;
            int h = (n_g - 1536) >> 6, d = n_g & 63;
            int bI = m0 >> 11;
            unsigned short* dst = vT + (size_t)((bI * 12 + h) * 64 + d) * 2048
                                  + (m0 & 2047) + mh * 64 + seg * 32;
            const unsigned short* src = Ts + drow * 72 + seg * 32;
#pragma unroll
            for (int j = 0; j < 4; j++)
                *(us8*)(dst + j * 8) = *(const us8*)(src + j * 8);
        }
    }
}

// ------------------------------------------------------------- fused attention
#define LOADKV(K0, Kf0, Kf1, Kf2, Kf3, Vf0, Vf1, Vf2, Vf3)            \
    {                                                                  \
        const unsigned short* kpt_ = kp + (size_t)(K0) * 64;           \
        Kf0 = *(const bf16x8*)(kpt_);                                  \
        Kf1 = *(const bf16x8*)(kpt_ + 16);                             \
        Kf2 = *(const bf16x8*)(kpt_ + 32);                             \
        Kf3 = *(const bf16x8*)(kpt_ + 48);                             \
        Vf0 = *(const bf16x8*)(vp + (K0));                             \
        Vf1 = *(const bf16x8*)(vp + (K0) + 16);                        \
        Vf2 = *(const bf16x8*)(vp + 65536 + (K0));                     \
        Vf3 = *(const bf16x8*)(vp + 65536 + (K0) + 16);                \
    }

#define BQUAD(J, S0, S1, S2, S3, MW, SROW, PKA, PKB)                                   \
    {                                                                                   \
        float e0 = fexp2(fminf(S0, 108.f)) * rinv;                                      \
        float e1 = fexp2(fminf(S1, 108.f)) * rinv;                                      \
        float e2 = fexp2(fminf(S2, 108.f)) * rinv;                                      \
        float e3 = fexp2(fminf(S3, 108.f)) * rinv;                                      \
        float a0 = ((MW >> (shv + 8 * (J) + 0)) & 1) ? e0 : 0.f;                        \
        float a1 = ((MW >> (shv + 8 * (J) + 1)) & 1) ? e1 : 0.f;                        \
        float a2 = ((MW >> (shv + 8 * (J) + 2)) & 1) ? e2 : 0.f;                        \
        float a3 = ((MW >> (shv + 8 * (J) + 3)) & 1) ? e3 : 0.f;                        \
        f32x4 av = {a0, a1, a2, a3};                                                    \
        *(f32x4*)((SROW) + 8 * (J)) = av;                                               \
        PKA = cvt_pk_bf16(a0, a1);                                                      \
        PKB = cvt_pk_bf16(a2, a3);                                                      \
    }

#define BTILE(Kf0, Kf1, Kf2, Kf3, Vf0, Vf1, Vf2, Vf3, MW, TT)                           \
    {                                                                                   \
        f32x16 s = {};                                                                  \
        __builtin_amdgcn_s_setprio(1);                                                  \
        s = mfma32(Kf0, qf0, s);                                                        \
        s = mfma32(Kf1, qf1, s);                                                        \
        s = mfma32(Kf2, qf2, s);                                                        \
        s = mfma32(Kf3, qf3, s);                                                        \
        __builtin_amdgcn_s_setprio(0);                                                  \
        float* srow = myS + l31 * 67 + (TT) * 32 + 4 * hi;                              \
        unsigned pk00, pk01, pk10, pk11, pk20, pk21, pk30, pk31;                        \
        BQUAD(0, s[0], s[1], s[2], s[3], MW, srow, pk00, pk01)                          \
        BQUAD(1, s[4], s[5], s[6], s[7], MW, srow, pk10, pk11)                          \
        BQUAD(2, s[8], s[9], s[10], s[11], MW, srow, pk20, pk21)                        \
        BQUAD(3, s[12], s[13], s[14], s[15], MW, srow, pk30, pk31)                      \
        __builtin_amdgcn_s_setprio(1);                                                  \
        {                                                                               \
            u32x2 sA = __builtin_amdgcn_permlane32_swap(pk00, pk10, false, false);      \
            u32x2 sB = __builtin_amdgcn_permlane32_swap(pk01, pk11, false, false);      \
            u32x4 bi = {sA[0], sB[0], sA[1], sB[1]};                                    \
            bf16x8 pf = __builtin_bit_cast(bf16x8, bi);                                 \
            c0 = mfma32(Vf0, pf, c0);                                                   \
            c1 = mfma32(Vf2, pf, c1);                                                   \
        }                                                                               \
        {                                                                               \
            u32x2 sA = __builtin_amdgcn_permlane32_swap(pk20, pk30, false, false);      \
            u32x2 sB = __builtin_amdgcn_permlane32_swap(pk21, pk31, false, false);      \
            u32x4 bi = {sA[0], sB[0], sA[1], sB[1]};                                    \
            bf16x8 pf = __builtin_bit_cast(bf16x8, bi);                                 \
            c0 = mfma32(Vf1, pf, c0);                                                   \
            c1 = mfma32(Vf3, pf, c1);                                                   \
        }                                                                               \
        __builtin_amdgcn_s_setprio(0);                                                  \
    }

// 3072 WGs (48 bh x 64 q-tiles, XCD-bijective) x 256 threads (4 waves).
// Phase A: reg-double-buffered K prefetch; 4 independent lsum partials
// (serial-chain depth /4); exp2 direct (log2e folded into Q).
// Phase B: per-wave private LDS staging (no barriers), K/V register
// double-buffered, next-phase loads issued BEFORE the NT store burst.
__global__ __launch_bounds__(256, 3) void k_attn(const unsigned short* __restrict__ qb,
                                                 const unsigned short* __restrict__ kbuf,
                                                 const unsigned short* __restrict__ vT,
                                                 const unsigned* __restrict__ maskbits,
                                                 float* __restrict__ attO,
                                                 unsigned short* __restrict__ ctx) {
    __shared__ __align__(16) char smem[34304 + 512 + 128];
    float* Ssm    = (float*)smem;
    float* l_part = (float*)(smem + 34304);   // [4][32]
    float* rowinv = (float*)(smem + 34816);   // [32]

    int tid = threadIdx.x, lane = tid & 63, w = tid >> 6;   // w = 0..3
    int l31 = lane & 31, hi = lane >> 5;
    int n = blockIdx.x;
    int xcd = n & 7, slot = n >> 3;
    int bh = xcd * 6 + (slot >> 6), qt = slot & 63;
    int b = bh / 12, h = bh - b * 12;
    int q0 = qt * 32;
    int shv = 4 * hi;

    const unsigned short* kbase = kbuf + (size_t)bh * 2048 * 64;
    const unsigned short* vbase = vT + (size_t)bh * 64 * 2048;
    const unsigned* mwrds = maskbits + b * 64;

    bf16x8 qf0, qf1, qf2, qf3;
    {
        const unsigned short* qp = qb + (size_t)(bh * 2048 + q0 + l31) * 64 + hi * 8;
        qf0 = *(const bf16x8*)(qp);
        qf1 = *(const bf16x8*)(qp + 16);
        qf2 = *(const bf16x8*)(qp + 32);
        qf3 = *(const bf16x8*)(qp + 48);
    }
    const unsigned short* kp = kbase + (size_t)l31 * 64 + hi * 8;
    const unsigned short* vp = vbase + (size_t)l31 * 2048 + hi * 8;

    // ---------------- Phase A: lsum, reg-dbuf, 4-way partials ----------------
    float lp0 = 0.f, lp1 = 0.f, lp2 = 0.f, lp3 = 0.f;
    {
        bf16x8 xa0, xa1, xa2, xa3, xb0, xb1, xb2, xb3;
        unsigned ma, mb2;
        int ks0 = w * 512;
        {
            const unsigned short* kpt = kp + (size_t)ks0 * 64;
            xa0 = *(const bf16x8*)(kpt);
            xa1 = *(const bf16x8*)(kpt + 16);
            xa2 = *(const bf16x8*)(kpt + 32);
            xa3 = *(const bf16x8*)(kpt + 48);
            ma = mwrds[ks0 >> 5];
        }
#pragma unroll 2
        for (int t = 0; t < 16; t++) {
            if (t < 15) {
                int nk = ks0 + (t + 1) * 32;
                const unsigned short* kpt = kp + (size_t)nk * 64;
                xb0 = *(const bf16x8*)(kpt);
                xb1 = *(const bf16x8*)(kpt + 16);
                xb2 = *(const bf16x8*)(kpt + 32);
                xb3 = *(const bf16x8*)(kpt + 48);
                mb2 = mwrds[nk >> 5];
            }
            f32x16 s = {};
            __builtin_amdgcn_s_setprio(1);
            s = mfma32(xa0, qf0, s);
            s = mfma32(xa1, qf1, s);
            s = mfma32(xa2, qf2, s);
            s = mfma32(xa3, qf3, s);
            __builtin_amdgcn_s_setprio(0);
            // 4 independent accumulator chains (one per k-quad)
#pragma unroll
            for (int j = 0; j < 4; j++) {
                float e0 = fexp2(fminf(s[4 * j + 0], 108.f));
                float e1 = fexp2(fminf(s[4 * j + 1], 108.f));
                float e2 = fexp2(fminf(s[4 * j + 2], 108.f));
                float e3 = fexp2(fminf(s[4 * j + 3], 108.f));
                float a0 = ((ma >> (shv + 8 * j + 0)) & 1) ? e0 : 0.f;
                float a1 = ((ma >> (shv + 8 * j + 1)) & 1) ? e1 : 0.f;
                float a2 = ((ma >> (shv + 8 * j + 2)) & 1) ? e2 : 0.f;
                float a3 = ((ma >> (shv + 8 * j + 3)) & 1) ? e3 : 0.f;
                if (j == 0) lp0 += (a0 + a1) + (a2 + a3);
                else if (j == 1) lp1 += (a0 + a1) + (a2 + a3);
                else if (j == 2) lp2 += (a0 + a1) + (a2 + a3);
                else lp3 += (a0 + a1) + (a2 + a3);
            }
            xa0 = xb0; xa1 = xb1; xa2 = xb2; xa3 = xb3; ma = mb2;
        }
    }
    float lsum = (lp0 + lp1) + (lp2 + lp3);
    lsum += __shfl_xor(lsum, 32, 64);
    if (hi == 0) l_part[w * 32 + l31] = lsum;
    __syncthreads();
    if (tid < 32)
        rowinv[tid] = 1.0f / (l_part[tid] + l_part[32 + tid] + l_part[64 + tid] + l_part[96 + tid]);
    __syncthreads();
    float rinv = rowinv[l31];

    // ---------------- Phase B: pipelined, barrier-free ----------------
    float* myS = Ssm + w * 2144;               // [32][67] f32, private to wave w
    float* attW = attO + (size_t)(bh * 2048 + q0) * 2048 + w * 64;

    bf16x8 ka0, ka1, ka2, ka3, va0, va1, va2, va3;
    bf16x8 kb0, kb1, kb2, kb3, vb0, vb1, vb2, vb3;
    unsigned mwA, mwB;
    {
        int k0 = w * 64;
        LOADKV(k0, ka0, ka1, ka2, ka3, va0, va1, va2, va3);
        mwA = mwrds[k0 >> 5];
        LOADKV(k0 + 32, kb0, kb1, kb2, kb3, vb0, vb1, vb2, vb3);
        mwB = mwrds[(k0 + 32) >> 5];
    }

    f32x16 c0 = {}, c1 = {};
    for (int p = 0; p < 8; p++) {
        BTILE(ka0, ka1, ka2, ka3, va0, va1, va2, va3, mwA, 0);
        BTILE(kb0, kb1, kb2, kb3, vb0, vb1, vb2, vb3, mwB, 1);
        if (p < 7) {   // prefetch next phase BEFORE this phase's stores
            int nk = (p + 1) * 256 + w * 64;
            LOADKV(nk, ka0, ka1, ka2, ka3, va0, va1, va2, va3);
            mwA = mwrds[nk >> 5];
            LOADKV(nk + 32, kb0, kb1, kb2, kb3, vb0, vb1, vb2, vb3);
            mwB = mwrds[(nk + 32) >> 5];
        }
        asm volatile("" ::: "memory");   // pin: loads above, stores below
        {
            int rsub = lane >> 4, c16 = lane & 15;
#pragma unroll
            for (int st = 0; st < 8; st++) {
                int row = st * 4 + rsub;
                f32x4 v = *(const f32x4*)(myS + row * 67 + c16 * 4);
                __builtin_nontemporal_store(v,
                    (f32x4*)(attW + (size_t)row * 2048 + p * 256 + c16 * 4));
            }
        }
    }

    // ---------------- ctx: two-step wave-partial reduction ----------------
    __syncthreads();
    {
        float* cw = Ssm + w * 2080 + l31 * 65;   // [4][32][65] overlay
#pragma unroll
        for (int r = 0; r < 16; r++) {
            int d = (r & 3) + 8 * (r >> 2) + 4 * hi;
            cw[d] = c0[r];
            cw[d + 32] = c1[r];
        }
    }
    __syncthreads();
    {
        int q = tid >> 3, d0 = (tid & 7) * 8;
        float a[8];
#pragma unroll
        for (int j = 0; j < 8; j++) a[j] = 0.f;
#pragma unroll
        for (int w2 = 0; w2 < 4; w2++) {
            const float* cw = Ssm + w2 * 2080 + q * 65 + d0;
#pragma unroll
            for (int j = 0; j < 8; j++) a[j] += cw[j];
        }
        us4 o0, o1;
        o0[0] = f2bf(a[0]); o0[1] = f2bf(a[1]); o0[2] = f2bf(a[2]); o0[3] = f2bf(a[3]);
        o1[0] = f2bf(a[4]); o1[1] = f2bf(a[5]); o1[2] = f2bf(a[6]); o1[3] = f2bf(a[7]);
        unsigned short* cp = ctx + (size_t)(b * 2048 + q0 + q) * 768 + h * 64 + d0;
        *(us4*)(cp) = o0;
        *(us4*)(cp + 4) = o1;
    }
}

// ------------------------------------------------------------- proj GEMM
__global__ __launch_bounds__(256) void k_gemm_proj(const unsigned short* __restrict__ A,
                                                   const unsigned short* __restrict__ Bt,
                                                   const float* __restrict__ bias,
                                                   float* __restrict__ out) {
    __shared__ __align__(16) char smem[32768];
    int tid = threadIdx.x, lane = tid & 63, w = tid >> 6;
    int l15 = lane & 15, g = lane >> 4;
    int m0 = blockIdx.x * 128, n0 = blockIdx.y * 128;
    int wr = w >> 1, wc = w & 1;
    f32x4 acc[4][4] = {};

    GSTAGE(smem, smem + 8192, A, Bt, 0);
    __syncthreads();
    int cur = 0;
    for (int t = 0; t < 24; t++) {
        if (t < 23)
            GSTAGE(smem + (cur ^ 1) * 16384, smem + (cur ^ 1) * 16384 + 8192, A, Bt, (t + 1) * 32);
        GCOMPUTE(smem + cur * 16384, smem + cur * 16384 + 8192);
        __syncthreads();
        cur ^= 1;
    }
#pragma unroll
    for (int nb = 0; nb < 4; nb++) {
        int n_g = n0 + wc * 64 + nb * 16 + l15;
        float bs = bias[n_g];
#pragma unroll
        for (int mb = 0; mb < 4; mb++) {
            f32x4 v = acc[mb][nb];
#pragma unroll
            for (int r = 0; r < 4; r++) {
                int m_g = m0 + wr * 64 + mb * 16 + g * 4 + r;
                out[(size_t)m_g * 768 + n_g] = v[r] + bs;
            }
        }
    }
}

// ---------------------------------------------------------------------------
extern "C" void kernel_launch(void* const* d_in, const int* in_sizes, int n_in,
                              void* d_out, int out_size, void* d_ws, size_t ws_size,
                              hipStream_t stream) {
    (void)in_sizes; (void)n_in; (void)out_size; (void)ws_size;
    const float* x      = (const float*)d_in[0];
    const int*   mask   = (const int*)d_in[1];
    const float* w_qkv  = (const float*)d_in[2];
    const float* b_qkv  = (const float*)d_in[3];
    const float* w_proj = (const float*)d_in[4];
    const float* b_proj = (const float*)d_in[5];
    const float* pb     = (const float*)d_in[6];
    (void)pb;

    float* out  = (float*)d_out;
    float* attO = out + (size_t)Bb * Nn * Cc;   // 6,291,456

    char* ws = (char*)d_ws;
    unsigned short* xb     = (unsigned short*)(ws);             // 12,582,912 B
    unsigned short* wqkvt  = (unsigned short*)(ws + 12582912);  //  3,538,944 B
    unsigned short* wprojt = (unsigned short*)(ws + 16121856);  //  1,179,648 B
    unsigned short* qbuf   = (unsigned short*)(ws + 17301504);  // 12,582,912 B
    unsigned short* kbuf   = (unsigned short*)(ws + 29884416);  // 12,582,912 B
    unsigned short* vtb    = (unsigned short*)(ws + 42467328);  // 12,582,912 B
    unsigned short* ctx    = (unsigned short*)(ws + 55050240);  // 12,582,912 B
    unsigned char*  mbits  = (unsigned char*)(ws + 67633152);   //      1,024 B

    k_cvt_bf16<<<6144, 256, 0, stream>>>(x, xb, 1572864);
    k_transpose_bf16<<<dim3(12, 36), 256, 0, stream>>>(w_qkv, wqkvt, 768, 2304);
    k_transpose_bf16<<<dim3(12, 12), 256, 0, stream>>>(w_proj, wprojt, 768, 768);
    k_maskbits<<<4, 256, 0, stream>>>(mask, mbits);
    k_gemm_qkv<<<dim3(64, 18), 256, 0, stream>>>(xb, wqkvt, b_qkv, qbuf, kbuf, vtb);
    k_attn<<<3072, 256, 0, stream>>>(qbuf, kbuf, vtb, (const unsigned*)mbits, attO, ctx);
    k_gemm_proj<<<dim3(64, 6), 256, 0, stream>>>(ctx, wprojt, b_proj, out);
}